// Round 3
// baseline (7738.283 us; speedup 1.0000x reference)
//
#include <hip/hip_runtime.h>

// LSTM_36807869726767 — round 7: round-4 shape + cached stores + wbl2 release.
// Round-6 post-mortem: halving L2 bytes/conflicts/VALU was all hidden under
// stall; the exposed cost is the agent-scope WRITE-THROUGH store drain before
// each barrier arrive (WRITE_SIZE 266->528MB when spans shrank). This round:
//  - plain cached stores for h (ack at local L2), ONE release("agent") fence
//    (buffer_wbl2) by tid0 before the barrier arrive. Write-once slots =>
//    consumers' plain loads can't see stale lines; same-XCD readers now hit
//    the producer's L2 line directly (round 4's atomics bypassed local L2).
//  - k-major conflict-free LDS weights (round-6 verified: 1.68e8 -> ~1e6).
//  - e-part weights back in LDS (round-6's global Wge stream was a suspect).
//  - fast sigmoid/tanh + bias fold (absmax-neutral per round 6), s_sleep(1),
//    unroll-8 h-loop + launch_bounds(256,1) for deeper prefetch at 1 wave/SIMD.
// B=64, S=512, E=512, H=1024, NCLS=10, PAD=0. All float I/O f32.

typedef _Float16 f16;
typedef __attribute__((ext_vector_type(8))) _Float16 f16x8;
typedef __attribute__((ext_vector_type(4))) float f32x4;

#define Bn 64
#define Sn 512
#define En 512
#define Hn 1024

// low16 of a|b pairs -> one dword (hi parts); high16 -> lo parts
#define PERM_HI 0x05040100u
#define PERM_LO 0x07060302u

__device__ __forceinline__ float fsig(float x) {
    return __builtin_amdgcn_rcpf(1.f + __expf(-x));
}
__device__ __forceinline__ float ftanh(float x) {
    return 2.f * __builtin_amdgcn_rcpf(1.f + __expf(-2.f * x)) - 1.f;
}

// ------------------------------------------------- gather e -> f16 [t][b][k]
__global__ __launch_bounds__(256) void gather_e_k(
    const int* __restrict__ x, const float* __restrict__ emb,
    f16* __restrict__ e16)
{
    size_t g = (size_t)blockIdx.x * 256 + threadIdx.x;
    int row = (int)(g >> 6);          // t*64 + b
    int ko  = (int)(g & 63) * 8;
    int t = row >> 6, b = row & 63;
    int tok = x[b * Sn + t];
    float4 a  = *(const float4*)&emb[(size_t)tok * En + ko];
    float4 a2 = *(const float4*)&emb[(size_t)tok * En + ko + 4];
    float v[8] = {a.x, a.y, a.z, a.w, a2.x, a2.y, a2.z, a2.w};
    f16x8 h;
    #pragma unroll
    for (int i = 0; i < 8; ++i) h[i] = (f16)v[i];
    *(f16x8*)&e16[(size_t)row * En + ko] = h;
}

// ------------------------------------------------------------- Wa f32 -> f16
__global__ __launch_bounds__(256) void split_wa_k(
    const float* __restrict__ Wa, f16* __restrict__ hi)
{
    size_t g = ((size_t)blockIdx.x * 256 + threadIdx.x) * 8;
    float4 a = *(const float4*)&Wa[g];
    float4 b = *(const float4*)&Wa[g + 4];
    float v[8] = {a.x, a.y, a.z, a.w, b.x, b.y, b.z, b.w};
    f16x8 h;
    #pragma unroll
    for (int i = 0; i < 8; ++i) h[i] = (f16)v[i];
    *(f16x8*)&hi[g] = h;
}

// ------------------------------------------- persistent LSTM recurrence
// 256 blocks x 256 thr (1 wave/SIMD, all CUs). Block bk owns h-dims
// d0=4*bk..d0+3 (16 gate rows). Wave w = 16 batch rows. h state: write-once
// slots h_pk[slot][b][k] u32 (hi|lo f16 packed); slot t = state entering step
// t; slot 0 zeroed; step t writes slot t+1 with PLAIN stores, made agent-
// visible by a release("agent") fence (buffer_wbl2) before the barrier add.
__global__ __launch_bounds__(256, 1) void lstm_persist_k(
    const f16* __restrict__ e16,      // [512*64][512]
    const float* __restrict__ Wg,     // [4096][1536] f32
    const float* __restrict__ bg,     // [4096]
    unsigned* __restrict__ h_pk,      // [513][64][1024] u32
    unsigned* __restrict__ bar)       // [16*32] group counters + [512] root
{
    // k-major [kchunk][16 rows][8]: zero pad, conflict-free ds_read_b128
    __shared__ f16 Wse[64 * 16 * 8];    // 16 KB (e-part, k=0..511)
    __shared__ f16 Wsh[128 * 16 * 8];   // 32 KB (h-part hi, k=512..1535)
    __shared__ f16 Wsl[128 * 16 * 8];   // 32 KB (h-part lo)

    const int tid = threadIdx.x;
    const int bk  = blockIdx.x;     // 0..255
    const int d0  = bk * 4;

    // ---- one-time: stage + split 16 weight rows (f32 -> f16 hi/lo), k-major
    {
        int n = tid >> 4, l16 = tid & 15;
        int j = (n >> 2) * 1024 + d0 + (n & 3);
        const float* src = Wg + (size_t)j * 1536;
        for (int k = l16 * 4; k < 1536; k += 64) {
            float4 v = *(const float4*)&src[k];
            float vv[4] = {v.x, v.y, v.z, v.w};
            #pragma unroll
            for (int i = 0; i < 4; ++i) {
                int kk = k + i;
                f16 hv = (f16)vv[i];
                f16 lv = (f16)(vv[i] - (float)hv);
                if (kk < 512) {
                    Wse[((kk >> 3) * 16 + n) * 8 + (kk & 7)] = hv;
                } else {
                    int kh = kk - 512;
                    int idx = ((kh >> 3) * 16 + n) * 8 + (kh & 7);
                    Wsh[idx] = hv;
                    Wsl[idx] = lv;
                }
            }
        }
    }
    __syncthreads();

    const int lane = tid & 63;
    const int w    = tid >> 6;
    const int cl   = lane & 15;
    const int q    = lane >> 4;
    const int b    = w * 16 + cl;
    const int ko   = q * 8;
    const int co   = cl & 3;
    const int jcol = (cl >> 2) * 1024 + d0 + (cl & 3);
    const float bgv = bg[jcol];

    const int wbase = (q * 16 + cl) * 8;   // lane base into k-major LDS
    const f16* Wse_r = &Wse[wbase];
    const f16* Wsh_r = &Wsh[wbase];
    const f16* Wsl_r = &Wsl[wbase];

    unsigned* grp  = &bar[(bk >> 4) * 32];
    unsigned* root = &bar[512];

    float cst[4] = {0.f, 0.f, 0.f, 0.f};
    int bail = 0;

    for (int t = 0; t < Sn; ++t) {
        // ---- e-part (independent of h) — runs while barrier settles
        const f16* Ae = e16 + ((size_t)t * 64 + b) * En + ko;
        f32x4 accE = {bgv, bgv, bgv, bgv};   // bias folded in
        #pragma unroll 8
        for (int ks = 0; ks < 16; ++ks) {
            f16x8 a  = *(const f16x8*)&Ae[ks * 32];
            f16x8 bb = *(const f16x8*)&Wse_r[ks * 512];
            accE = __builtin_amdgcn_mfma_f32_16x16x32_f16(a, bb, accE, 0, 0, 0);
        }

        // ---- wait for step t-1 (root >= 16*t); relaxed spin, no acquire
        if (tid == 0 && t > 0 && !bail) {
            unsigned tgt = 16u * (unsigned)t;
            long spins = 0;
            while (__hip_atomic_load(root, __ATOMIC_RELAXED,
                                     __HIP_MEMORY_SCOPE_AGENT) < tgt) {
                __builtin_amdgcn_s_sleep(1);
                if (++spins > (1L << 24)) { bail = 1; break; }
            }
        }
        __syncthreads();
        __builtin_amdgcn_fence(__ATOMIC_ACQUIRE, "workgroup"); // no buffer_inv
        __asm__ __volatile__("" ::: "memory");

        // ---- h-part: normal cached loads of write-once slot t (L2 dedups)
        const unsigned* Ap = h_pk + ((size_t)t * 64 + b) * Hn + ko;
        f32x4 acc1 = {0.f, 0.f, 0.f, 0.f};
        f32x4 acc2 = {0.f, 0.f, 0.f, 0.f};
        f32x4 acc3 = {0.f, 0.f, 0.f, 0.f};
        #pragma unroll 8
        for (int ks = 0; ks < 32; ++ks) {
            uint4 p0 = *(const uint4*)&Ap[ks * 32];
            uint4 p1 = *(const uint4*)&Ap[ks * 32 + 4];
            union { unsigned u[4]; f16x8 v; } Ah, Al;
            Ah.u[0] = __builtin_amdgcn_perm(p0.y, p0.x, PERM_HI);
            Ah.u[1] = __builtin_amdgcn_perm(p0.w, p0.z, PERM_HI);
            Ah.u[2] = __builtin_amdgcn_perm(p1.y, p1.x, PERM_HI);
            Ah.u[3] = __builtin_amdgcn_perm(p1.w, p1.z, PERM_HI);
            Al.u[0] = __builtin_amdgcn_perm(p0.y, p0.x, PERM_LO);
            Al.u[1] = __builtin_amdgcn_perm(p0.w, p0.z, PERM_LO);
            Al.u[2] = __builtin_amdgcn_perm(p1.y, p1.x, PERM_LO);
            Al.u[3] = __builtin_amdgcn_perm(p1.w, p1.z, PERM_LO);
            f16x8 bh = *(const f16x8*)&Wsh_r[ks * 512];
            f16x8 bl = *(const f16x8*)&Wsl_r[ks * 512];
            acc1 = __builtin_amdgcn_mfma_f32_16x16x32_f16(Ah.v, bh, acc1, 0, 0, 0);
            acc2 = __builtin_amdgcn_mfma_f32_16x16x32_f16(Ah.v, bl, acc2, 0, 0, 0);
            acc3 = __builtin_amdgcn_mfma_f32_16x16x32_f16(Al.v, bh, acc3, 0, 0, 0);
        }
        f32x4 acc;
        #pragma unroll
        for (int r = 0; r < 4; ++r)
            acc[r] = (accE[r] + acc1[r]) + (acc2[r] + acc3[r]);

        // ---- cell update. D: col=cl (gate jcol), row=q*4+r (batch w*16+q*4+r)
        #pragma unroll
        for (int r = 0; r < 4; ++r) {
            float av = acc[r];
            float iv = __shfl(av, (lane & 48) | co,      64);
            float fv = __shfl(av, (lane & 48) | 4 | co,  64);
            float gv = __shfl(av, (lane & 48) | 8 | co,  64);
            float ov = __shfl(av, (lane & 48) | 12 | co, 64);
            if (cl < 4) {
                int d  = d0 + co;
                int br = w * 16 + q * 4 + r;
                float i_ = fsig(iv);
                float f_ = fsig(fv);
                float g_ = ftanh(gv);
                float o_ = fsig(ov);
                float cn = f_ * cst[r] + i_ * g_;
                cst[r] = cn;
                float hn = o_ * ftanh(cn);
                f16 hh = (f16)hn;
                f16 hl = (f16)(hn - (float)hh);
                unsigned pkv = (unsigned)__builtin_bit_cast(unsigned short, hh)
                             | ((unsigned)__builtin_bit_cast(unsigned short, hl) << 16);
                // PLAIN store: acks at local L2; wbl2 below publishes to L3
                h_pk[((size_t)(t + 1) * 64 + br) * Hn + d] = pkv;
            }
        }

        // ---- arrive: syncthreads drains stores to L2; tid0 publishes (wbl2)
        __syncthreads();
        __asm__ __volatile__("" ::: "memory");
        if (tid == 0) {
            __builtin_amdgcn_fence(__ATOMIC_RELEASE, "agent"); // buffer_wbl2
            unsigned prev = __hip_atomic_fetch_add(grp, 1u, __ATOMIC_RELAXED,
                                                   __HIP_MEMORY_SCOPE_AGENT);
            if ((prev & 15u) == 15u)   // 16th arrival of this step in group
                __hip_atomic_fetch_add(root, 1u, __ATOMIC_RELAXED,
                                       __HIP_MEMORY_SCOPE_AGENT);
        }
    }
}

// ---------------------------------------------------------------- energy GEMM
// rows r = t*64+b (h_pk linear row r+64); energy[r] += tanh(row.Wa[d]) * va[d]
__global__ __launch_bounds__(256) void energy_k(
    const unsigned* __restrict__ h_pk,  // [513*64][1024] u32
    const f16* __restrict__ Wa_hi,      // [H][H]
    const float* __restrict__ va,       // [H]
    float* __restrict__ energy)         // [B*S] (r-indexed), pre-zeroed
{
    __shared__ f16 Was[128][136];
    const int bid = blockIdx.x;
    const int rb = bid >> 3;
    const int nb = bid & 7;
    const int tid = threadIdx.x;
    const int lane = tid & 63, w = tid >> 6, cl = lane & 15, q = lane >> 4;
    const int r0 = rb * 64 + w * 16 + cl;

    f32x4 acc[8];
    #pragma unroll
    for (int i = 0; i < 8; ++i) acc[i] = (f32x4){0.f, 0.f, 0.f, 0.f};

    for (int kc = 0; kc < 8; ++kc) {
        __syncthreads();
        for (int i = tid; i < 128 * 16; i += 256) {
            int dd = i >> 4;
            int kv = (i & 15) * 8;
            *(f16x8*)&Was[dd][kv] =
                *(const f16x8*)&Wa_hi[(size_t)(nb * 128 + dd) * Hn + kc * 128 + kv];
        }
        __syncthreads();
        const unsigned* A = h_pk + (size_t)(r0 + 64) * Hn + kc * 128;
        #pragma unroll
        for (int ks = 0; ks < 4; ++ks) {
            uint4 p0 = *(const uint4*)&A[ks * 32 + q * 8];
            uint4 p1 = *(const uint4*)&A[ks * 32 + q * 8 + 4];
            union { unsigned u[4]; f16x8 v; } Ah;
            Ah.u[0] = __builtin_amdgcn_perm(p0.y, p0.x, PERM_HI);
            Ah.u[1] = __builtin_amdgcn_perm(p0.w, p0.z, PERM_HI);
            Ah.u[2] = __builtin_amdgcn_perm(p1.y, p1.x, PERM_HI);
            Ah.u[3] = __builtin_amdgcn_perm(p1.w, p1.z, PERM_HI);
            #pragma unroll
            for (int nt = 0; nt < 8; ++nt) {
                f16x8 bb = *(const f16x8*)&Was[nt * 16 + cl][ks * 32 + q * 8];
                acc[nt] = __builtin_amdgcn_mfma_f32_16x16x32_f16(Ah.v, bb, acc[nt], 0, 0, 0);
            }
        }
    }

    float rowsum[4] = {0.f, 0.f, 0.f, 0.f};
    #pragma unroll
    for (int nt = 0; nt < 8; ++nt) {
        float vv = va[nb * 128 + nt * 16 + cl];
        #pragma unroll
        for (int r = 0; r < 4; ++r)
            rowsum[r] += tanhf(acc[nt][r]) * vv;
    }
    #pragma unroll
    for (int m = 1; m < 16; m <<= 1)
        #pragma unroll
        for (int r = 0; r < 4; ++r)
            rowsum[r] += __shfl_xor(rowsum[r], m, 64);
    if (cl == 0) {
        #pragma unroll
        for (int r = 0; r < 4; ++r)
            atomicAdd(&energy[(size_t)rb * 64 + w * 16 + q * 4 + r], rowsum[r]);
    }
}

// ------------------------------------------------- masked softmax + context
// energy index for (b,s) = s*64 + b
__global__ __launch_bounds__(256) void softctx_k(
    const float* __restrict__ energy, const int* __restrict__ x,
    const unsigned* __restrict__ h_pk,
    float* __restrict__ context)   // [B][H]
{
    __shared__ float sm[512];
    __shared__ float red[256];
    const int b = blockIdx.x, tid = threadIdx.x;
    const int s0 = tid, s1 = tid + 256;
    float e0 = (x[b * Sn + s0] != 0) ? energy[s0 * 64 + b] : -1e10f;
    float e1 = (x[b * Sn + s1] != 0) ? energy[s1 * 64 + b] : -1e10f;
    red[tid] = fmaxf(e0, e1);
    __syncthreads();
    for (int st = 128; st > 0; st >>= 1) {
        if (tid < st) red[tid] = fmaxf(red[tid], red[tid + st]);
        __syncthreads();
    }
    float M = red[0];
    __syncthreads();
    float p0 = expf(e0 - M), p1 = expf(e1 - M);
    red[tid] = p0 + p1;
    __syncthreads();
    for (int st = 128; st > 0; st >>= 1) {
        if (tid < st) red[tid] += red[tid + st];
        __syncthreads();
    }
    float inv = 1.f / red[0];
    sm[s0] = p0 * inv; sm[s1] = p1 * inv;
    __syncthreads();

    const int d0v = tid * 4;
    float a0 = 0.f, a1 = 0.f, a2 = 0.f, a3 = 0.f;
    for (int s = 0; s < Sn; ++s) {
        float at = sm[s];
        uint4 pv = *(const uint4*)&h_pk[((size_t)(s + 1) * 64 + b) * Hn + d0v];
        union { unsigned u; _Float16 h[2]; } c0, c1, c2, c3;
        c0.u = pv.x; c1.u = pv.y; c2.u = pv.z; c3.u = pv.w;
        a0 += at * ((float)c0.h[0] + (float)c0.h[1]);
        a1 += at * ((float)c1.h[0] + (float)c1.h[1]);
        a2 += at * ((float)c2.h[0] + (float)c2.h[1]);
        a3 += at * ((float)c3.h[0] + (float)c3.h[1]);
    }
    float* cp = context + (size_t)b * Hn + d0v;
    cp[0] = a0; cp[1] = a1; cp[2] = a2; cp[3] = a3;
}

// ---------------------------------------------------------------- logits
__global__ __launch_bounds__(256) void logits_k(
    const float* __restrict__ context, const float* __restrict__ WV,
    const float* __restrict__ bV, float* __restrict__ out)
{
    __shared__ float red[10][257];
    const int b = blockIdx.x, tid = threadIdx.x;
    const int d0v = tid * 4;
    float4 cv = *(const float4*)&context[(size_t)b * Hn + d0v];
    #pragma unroll
    for (int cls = 0; cls < 10; ++cls) {
        float4 wv = *(const float4*)&WV[cls * Hn + d0v];
        red[cls][tid] = cv.x * wv.x + cv.y * wv.y + cv.z * wv.z + cv.w * wv.w;
    }
    __syncthreads();
    for (int st = 128; st > 0; st >>= 1) {
        if (tid < st)
            #pragma unroll
            for (int cls = 0; cls < 10; ++cls)
                red[cls][tid] += red[cls][tid + st];
        __syncthreads();
    }
    if (tid < 10) out[b * 10 + tid] = red[tid][0] + bV[tid];
}

// ---------------------------------------------------------------- launch
extern "C" void kernel_launch(void* const* d_in, const int* in_sizes, int n_in,
                              void* d_out, int out_size, void* d_ws, size_t ws_size,
                              hipStream_t stream)
{
    const int*   x   = (const int*)d_in[0];
    const float* emb = (const float*)d_in[1];
    const float* Wg  = (const float*)d_in[2];
    const float* bg  = (const float*)d_in[3];
    const float* Wa  = (const float*)d_in[4];
    const float* va  = (const float*)d_in[5];
    const float* WV  = (const float*)d_in[6];
    const float* bV  = (const float*)d_in[7];
    float* out = (float*)d_out;

    char* ws = (char*)d_ws;
    size_t o = 0;
    auto alloc = [&](size_t bytes) { void* p = ws + o; o += (bytes + 255) & ~(size_t)255; return p; };
    f16*      e16   = (f16*)alloc((size_t)Sn * Bn * En * 2);        // 33.5 MB
    f16*      Wa_hi = (f16*)alloc((size_t)Hn * Hn * 2);             // 2 MB
    unsigned* h_pk  = (unsigned*)alloc((size_t)(Sn + 1) * Bn * Hn * 4); // 134.5 MB
    float*    energy= (float*)alloc((size_t)Bn * Sn * 4);
    float*    ctx   = (float*)alloc((size_t)Bn * Hn * 4);
    unsigned* bar   = (unsigned*)alloc(4096);
    // total ~170 MB

    hipMemsetAsync(h_pk, 0, (size_t)Bn * Hn * 4, stream);   // slot 0 = zeros
    hipMemsetAsync(energy, 0, (size_t)Bn * Sn * 4, stream);
    hipMemsetAsync(bar, 0, 4096, stream);

    gather_e_k<<<8192, 256, 0, stream>>>(x, emb, e16);
    split_wa_k<<<512, 256, 0, stream>>>(Wa, Wa_hi);

    lstm_persist_k<<<256, 256, 0, stream>>>(e16, Wg, bg, h_pk, bar);

    energy_k<<<512 * 8, 256, 0, stream>>>(h_pk, Wa_hi, va, energy);
    softctx_k<<<Bn, 256, 0, stream>>>(energy, x, h_pk, ctx);
    logits_k<<<Bn, 256, 0, stream>>>(ctx, WV, bV, out);
}

// Round 4
// 5886.926 us; speedup vs baseline: 1.3145x; 1.3145x over previous
//
#include <hip/hip_runtime.h>

// LSTM_36807869726767 — round 8: exact round-4 structure + the two verified
// micro-wins only.
// Round-7 post-mortem: per-step release("agent") fence = buffer_wbl2 full-L2
// walk on the arrive path, +6800 cyc/step with byte counters identical to
// round 4 -> the fence itself was the cost. Round 4's relaxed agent-scope
// atomic stores (write-through, drain overlapped across 16 stores, no fence)
// remain the cheapest correct publish. This round changes vs round 4 ONLY:
//  - k-major conflict-free LDS weights (verified: conflicts 1.68e8 -> ~2e6,
//    ~1280 wasted cycles/block-step removed)
//  - fast sigmoid/tanh + bias folded into accE init (VALU cycles halved,
//    absmax-neutral in rounds 6 and 7)
// Everything else (stores, barrier, sleep(4), unroll 4, launch bounds,
// decomposition 256 blocks x 256 thr, 64 batch x 16 gate rows) is round 4.
// B=64, S=512, E=512, H=1024, NCLS=10, PAD=0. All float I/O f32.

typedef _Float16 f16;
typedef __attribute__((ext_vector_type(8))) _Float16 f16x8;
typedef __attribute__((ext_vector_type(4))) float f32x4;

#define Bn 64
#define Sn 512
#define En 512
#define Hn 1024

// low16 of a|b pairs -> one dword (hi parts); high16 -> lo parts
#define PERM_HI 0x05040100u
#define PERM_LO 0x07060302u

__device__ __forceinline__ float fsig(float x) {
    return __builtin_amdgcn_rcpf(1.f + __expf(-x));
}
__device__ __forceinline__ float ftanh(float x) {
    return 2.f * __builtin_amdgcn_rcpf(1.f + __expf(-2.f * x)) - 1.f;
}

// ------------------------------------------------- gather e -> f16 [t][b][k]
__global__ __launch_bounds__(256) void gather_e_k(
    const int* __restrict__ x, const float* __restrict__ emb,
    f16* __restrict__ e16)
{
    size_t g = (size_t)blockIdx.x * 256 + threadIdx.x;
    int row = (int)(g >> 6);          // t*64 + b
    int ko  = (int)(g & 63) * 8;
    int t = row >> 6, b = row & 63;
    int tok = x[b * Sn + t];
    float4 a  = *(const float4*)&emb[(size_t)tok * En + ko];
    float4 a2 = *(const float4*)&emb[(size_t)tok * En + ko + 4];
    float v[8] = {a.x, a.y, a.z, a.w, a2.x, a2.y, a2.z, a2.w};
    f16x8 h;
    #pragma unroll
    for (int i = 0; i < 8; ++i) h[i] = (f16)v[i];
    *(f16x8*)&e16[(size_t)row * En + ko] = h;
}

// ------------------------------------------------------------- Wa f32 -> f16
__global__ __launch_bounds__(256) void split_wa_k(
    const float* __restrict__ Wa, f16* __restrict__ hi)
{
    size_t g = ((size_t)blockIdx.x * 256 + threadIdx.x) * 8;
    float4 a = *(const float4*)&Wa[g];
    float4 b = *(const float4*)&Wa[g + 4];
    float v[8] = {a.x, a.y, a.z, a.w, b.x, b.y, b.z, b.w};
    f16x8 h;
    #pragma unroll
    for (int i = 0; i < 8; ++i) h[i] = (f16)v[i];
    *(f16x8*)&hi[g] = h;
}

// ------------------------------------------- persistent LSTM recurrence
// 256 blocks x 256 thr (1 wave/SIMD, all CUs). Block bk owns h-dims
// d0=4*bk..d0+3 (16 gate rows). Wave w = 16 batch rows. h state: write-once
// slots h_pk[slot][b][k] u32 (hi|lo f16 packed); slot t = state entering
// step t; slot 0 zeroed; step t writes slot t+1 via relaxed agent-scope
// atomic stores (write-through to coherence point; readers use normal cached
// loads of write-once lines -> no stale data, no fences needed).
__global__ __launch_bounds__(256) void lstm_persist_k(
    const f16* __restrict__ e16,      // [512*64][512]
    const float* __restrict__ Wg,     // [4096][1536] f32
    const float* __restrict__ bg,     // [4096]
    unsigned* __restrict__ h_pk,      // [513][64][1024] u32
    unsigned* __restrict__ bar)       // [16*32] group counters + [512] root
{
    // k-major [kchunk][16 rows][8]: zero pad, conflict-free ds_read_b128
    __shared__ f16 Wse[64 * 16 * 8];    // 16 KB (e-part, k=0..511)
    __shared__ f16 Wsh[128 * 16 * 8];   // 32 KB (h-part hi, k=512..1535)
    __shared__ f16 Wsl[128 * 16 * 8];   // 32 KB (h-part lo)

    const int tid = threadIdx.x;
    const int bk  = blockIdx.x;     // 0..255
    const int d0  = bk * 4;

    // ---- one-time: stage + split 16 weight rows (f32 -> f16 hi/lo), k-major
    {
        int n = tid >> 4, l16 = tid & 15;
        int j = (n >> 2) * 1024 + d0 + (n & 3);
        const float* src = Wg + (size_t)j * 1536;
        for (int k = l16 * 4; k < 1536; k += 64) {
            float4 v = *(const float4*)&src[k];
            float vv[4] = {v.x, v.y, v.z, v.w};
            #pragma unroll
            for (int i = 0; i < 4; ++i) {
                int kk = k + i;
                f16 hv = (f16)vv[i];
                f16 lv = (f16)(vv[i] - (float)hv);
                if (kk < 512) {
                    Wse[((kk >> 3) * 16 + n) * 8 + (kk & 7)] = hv;
                } else {
                    int kh = kk - 512;
                    int idx = ((kh >> 3) * 16 + n) * 8 + (kh & 7);
                    Wsh[idx] = hv;
                    Wsl[idx] = lv;
                }
            }
        }
    }
    __syncthreads();

    const int lane = tid & 63;
    const int w    = tid >> 6;
    const int cl   = lane & 15;
    const int q    = lane >> 4;
    const int b    = w * 16 + cl;
    const int ko   = q * 8;
    const int co   = cl & 3;
    const int jcol = (cl >> 2) * 1024 + d0 + (cl & 3);
    const float bgv = bg[jcol];

    const int wbase = (q * 16 + cl) * 8;   // lane base into k-major LDS
    const f16* Wse_r = &Wse[wbase];
    const f16* Wsh_r = &Wsh[wbase];
    const f16* Wsl_r = &Wsl[wbase];

    unsigned* grp  = &bar[(bk >> 4) * 32];
    unsigned* root = &bar[512];

    float cst[4] = {0.f, 0.f, 0.f, 0.f};
    int bail = 0;

    for (int t = 0; t < Sn; ++t) {
        // ---- e-part (independent of h) — runs while barrier settles
        const f16* Ae = e16 + ((size_t)t * 64 + b) * En + ko;
        f32x4 accE = {bgv, bgv, bgv, bgv};   // bias folded in
        #pragma unroll 4
        for (int ks = 0; ks < 16; ++ks) {
            f16x8 a  = *(const f16x8*)&Ae[ks * 32];
            f16x8 bb = *(const f16x8*)&Wse_r[ks * 512];
            accE = __builtin_amdgcn_mfma_f32_16x16x32_f16(a, bb, accE, 0, 0, 0);
        }

        // ---- wait for step t-1 (root >= 16*t); relaxed spin, no acquire
        if (tid == 0 && t > 0 && !bail) {
            unsigned tgt = 16u * (unsigned)t;
            long spins = 0;
            while (__hip_atomic_load(root, __ATOMIC_RELAXED,
                                     __HIP_MEMORY_SCOPE_AGENT) < tgt) {
                __builtin_amdgcn_s_sleep(4);
                if (++spins > (1L << 24)) { bail = 1; break; }
            }
        }
        __syncthreads();
        __builtin_amdgcn_fence(__ATOMIC_ACQUIRE, "workgroup"); // no buffer_inv
        __asm__ __volatile__("" ::: "memory");

        // ---- h-part: normal cached loads of write-once slot t (L2 dedups)
        const unsigned* Ap = h_pk + ((size_t)t * 64 + b) * Hn + ko;
        f32x4 acc1 = {0.f, 0.f, 0.f, 0.f};
        f32x4 acc2 = {0.f, 0.f, 0.f, 0.f};
        f32x4 acc3 = {0.f, 0.f, 0.f, 0.f};
        #pragma unroll 4
        for (int ks = 0; ks < 32; ++ks) {
            uint4 p0 = *(const uint4*)&Ap[ks * 32];
            uint4 p1 = *(const uint4*)&Ap[ks * 32 + 4];
            union { unsigned u[4]; f16x8 v; } Ah, Al;
            Ah.u[0] = __builtin_amdgcn_perm(p0.y, p0.x, PERM_HI);
            Ah.u[1] = __builtin_amdgcn_perm(p0.w, p0.z, PERM_HI);
            Ah.u[2] = __builtin_amdgcn_perm(p1.y, p1.x, PERM_HI);
            Ah.u[3] = __builtin_amdgcn_perm(p1.w, p1.z, PERM_HI);
            Al.u[0] = __builtin_amdgcn_perm(p0.y, p0.x, PERM_LO);
            Al.u[1] = __builtin_amdgcn_perm(p0.w, p0.z, PERM_LO);
            Al.u[2] = __builtin_amdgcn_perm(p1.y, p1.x, PERM_LO);
            Al.u[3] = __builtin_amdgcn_perm(p1.w, p1.z, PERM_LO);
            f16x8 bh = *(const f16x8*)&Wsh_r[ks * 512];
            f16x8 bl = *(const f16x8*)&Wsl_r[ks * 512];
            acc1 = __builtin_amdgcn_mfma_f32_16x16x32_f16(Ah.v, bh, acc1, 0, 0, 0);
            acc2 = __builtin_amdgcn_mfma_f32_16x16x32_f16(Ah.v, bl, acc2, 0, 0, 0);
            acc3 = __builtin_amdgcn_mfma_f32_16x16x32_f16(Al.v, bh, acc3, 0, 0, 0);
        }
        f32x4 acc;
        #pragma unroll
        for (int r = 0; r < 4; ++r)
            acc[r] = (accE[r] + acc1[r]) + (acc2[r] + acc3[r]);

        // ---- cell update. D: col=cl (gate jcol), row=q*4+r (batch w*16+q*4+r)
        #pragma unroll
        for (int r = 0; r < 4; ++r) {
            float av = acc[r];
            float iv = __shfl(av, (lane & 48) | co,      64);
            float fv = __shfl(av, (lane & 48) | 4 | co,  64);
            float gv = __shfl(av, (lane & 48) | 8 | co,  64);
            float ov = __shfl(av, (lane & 48) | 12 | co, 64);
            if (cl < 4) {
                int d  = d0 + co;
                int br = w * 16 + q * 4 + r;
                float i_ = fsig(iv);
                float f_ = fsig(fv);
                float g_ = ftanh(gv);
                float o_ = fsig(ov);
                float cn = f_ * cst[r] + i_ * g_;
                cst[r] = cn;
                float hn = o_ * ftanh(cn);
                f16 hh = (f16)hn;
                f16 hl = (f16)(hn - (float)hh);
                unsigned pkv = (unsigned)__builtin_bit_cast(unsigned short, hh)
                             | ((unsigned)__builtin_bit_cast(unsigned short, hl) << 16);
                // to coherence point (sc0 sc1), bypasses L2 -> L2 stays clean
                __hip_atomic_store(&h_pk[((size_t)(t + 1) * 64 + br) * Hn + d],
                                   pkv, __ATOMIC_RELAXED, __HIP_MEMORY_SCOPE_AGENT);
            }
        }

        // ---- arrive: __syncthreads drains vmcnt(0) per wave (stores acked)
        __syncthreads();
        __asm__ __volatile__("" ::: "memory");
        if (tid == 0) {
            unsigned prev = __hip_atomic_fetch_add(grp, 1u, __ATOMIC_RELAXED,
                                                   __HIP_MEMORY_SCOPE_AGENT);
            if ((prev & 15u) == 15u)   // 16th arrival of this step in group
                __hip_atomic_fetch_add(root, 1u, __ATOMIC_RELAXED,
                                       __HIP_MEMORY_SCOPE_AGENT);
        }
    }
}

// ---------------------------------------------------------------- energy GEMM
// rows r = t*64+b (h_pk linear row r+64); energy[r] += tanh(row.Wa[d]) * va[d]
__global__ __launch_bounds__(256) void energy_k(
    const unsigned* __restrict__ h_pk,  // [513*64][1024] u32
    const f16* __restrict__ Wa_hi,      // [H][H]
    const float* __restrict__ va,       // [H]
    float* __restrict__ energy)         // [B*S] (r-indexed), pre-zeroed
{
    __shared__ f16 Was[128][136];
    const int bid = blockIdx.x;
    const int rb = bid >> 3;
    const int nb = bid & 7;
    const int tid = threadIdx.x;
    const int lane = tid & 63, w = tid >> 6, cl = lane & 15, q = lane >> 4;
    const int r0 = rb * 64 + w * 16 + cl;

    f32x4 acc[8];
    #pragma unroll
    for (int i = 0; i < 8; ++i) acc[i] = (f32x4){0.f, 0.f, 0.f, 0.f};

    for (int kc = 0; kc < 8; ++kc) {
        __syncthreads();
        for (int i = tid; i < 128 * 16; i += 256) {
            int dd = i >> 4;
            int kv = (i & 15) * 8;
            *(f16x8*)&Was[dd][kv] =
                *(const f16x8*)&Wa_hi[(size_t)(nb * 128 + dd) * Hn + kc * 128 + kv];
        }
        __syncthreads();
        const unsigned* A = h_pk + (size_t)(r0 + 64) * Hn + kc * 128;
        #pragma unroll
        for (int ks = 0; ks < 4; ++ks) {
            uint4 p0 = *(const uint4*)&A[ks * 32 + q * 8];
            uint4 p1 = *(const uint4*)&A[ks * 32 + q * 8 + 4];
            union { unsigned u[4]; f16x8 v; } Ah;
            Ah.u[0] = __builtin_amdgcn_perm(p0.y, p0.x, PERM_HI);
            Ah.u[1] = __builtin_amdgcn_perm(p0.w, p0.z, PERM_HI);
            Ah.u[2] = __builtin_amdgcn_perm(p1.y, p1.x, PERM_HI);
            Ah.u[3] = __builtin_amdgcn_perm(p1.w, p1.z, PERM_HI);
            #pragma unroll
            for (int nt = 0; nt < 8; ++nt) {
                f16x8 bb = *(const f16x8*)&Was[nt * 16 + cl][ks * 32 + q * 8];
                acc[nt] = __builtin_amdgcn_mfma_f32_16x16x32_f16(Ah.v, bb, acc[nt], 0, 0, 0);
            }
        }
    }

    float rowsum[4] = {0.f, 0.f, 0.f, 0.f};
    #pragma unroll
    for (int nt = 0; nt < 8; ++nt) {
        float vv = va[nb * 128 + nt * 16 + cl];
        #pragma unroll
        for (int r = 0; r < 4; ++r)
            rowsum[r] += tanhf(acc[nt][r]) * vv;
    }
    #pragma unroll
    for (int m = 1; m < 16; m <<= 1)
        #pragma unroll
        for (int r = 0; r < 4; ++r)
            rowsum[r] += __shfl_xor(rowsum[r], m, 64);
    if (cl == 0) {
        #pragma unroll
        for (int r = 0; r < 4; ++r)
            atomicAdd(&energy[(size_t)rb * 64 + w * 16 + q * 4 + r], rowsum[r]);
    }
}

// ------------------------------------------------- masked softmax + context
// energy index for (b,s) = s*64 + b
__global__ __launch_bounds__(256) void softctx_k(
    const float* __restrict__ energy, const int* __restrict__ x,
    const unsigned* __restrict__ h_pk,
    float* __restrict__ context)   // [B][H]
{
    __shared__ float sm[512];
    __shared__ float red[256];
    const int b = blockIdx.x, tid = threadIdx.x;
    const int s0 = tid, s1 = tid + 256;
    float e0 = (x[b * Sn + s0] != 0) ? energy[s0 * 64 + b] : -1e10f;
    float e1 = (x[b * Sn + s1] != 0) ? energy[s1 * 64 + b] : -1e10f;
    red[tid] = fmaxf(e0, e1);
    __syncthreads();
    for (int st = 128; st > 0; st >>= 1) {
        if (tid < st) red[tid] = fmaxf(red[tid], red[tid + st]);
        __syncthreads();
    }
    float M = red[0];
    __syncthreads();
    float p0 = expf(e0 - M), p1 = expf(e1 - M);
    red[tid] = p0 + p1;
    __syncthreads();
    for (int st = 128; st > 0; st >>= 1) {
        if (tid < st) red[tid] += red[tid + st];
        __syncthreads();
    }
    float inv = 1.f / red[0];
    sm[s0] = p0 * inv; sm[s1] = p1 * inv;
    __syncthreads();

    const int d0v = tid * 4;
    float a0 = 0.f, a1 = 0.f, a2 = 0.f, a3 = 0.f;
    for (int s = 0; s < Sn; ++s) {
        float at = sm[s];
        uint4 pv = *(const uint4*)&h_pk[((size_t)(s + 1) * 64 + b) * Hn + d0v];
        union { unsigned u; _Float16 h[2]; } c0, c1, c2, c3;
        c0.u = pv.x; c1.u = pv.y; c2.u = pv.z; c3.u = pv.w;
        a0 += at * ((float)c0.h[0] + (float)c0.h[1]);
        a1 += at * ((float)c1.h[0] + (float)c1.h[1]);
        a2 += at * ((float)c2.h[0] + (float)c2.h[1]);
        a3 += at * ((float)c3.h[0] + (float)c3.h[1]);
    }
    float* cp = context + (size_t)b * Hn + d0v;
    cp[0] = a0; cp[1] = a1; cp[2] = a2; cp[3] = a3;
}

// ---------------------------------------------------------------- logits
__global__ __launch_bounds__(256) void logits_k(
    const float* __restrict__ context, const float* __restrict__ WV,
    const float* __restrict__ bV, float* __restrict__ out)
{
    __shared__ float red[10][257];
    const int b = blockIdx.x, tid = threadIdx.x;
    const int d0v = tid * 4;
    float4 cv = *(const float4*)&context[(size_t)b * Hn + d0v];
    #pragma unroll
    for (int cls = 0; cls < 10; ++cls) {
        float4 wv = *(const float4*)&WV[cls * Hn + d0v];
        red[cls][tid] = cv.x * wv.x + cv.y * wv.y + cv.z * wv.z + cv.w * wv.w;
    }
    __syncthreads();
    for (int st = 128; st > 0; st >>= 1) {
        if (tid < st)
            #pragma unroll
            for (int cls = 0; cls < 10; ++cls)
                red[cls][tid] += red[cls][tid + st];
        __syncthreads();
    }
    if (tid < 10) out[b * 10 + tid] = red[tid][0] + bV[tid];
}

// ---------------------------------------------------------------- launch
extern "C" void kernel_launch(void* const* d_in, const int* in_sizes, int n_in,
                              void* d_out, int out_size, void* d_ws, size_t ws_size,
                              hipStream_t stream)
{
    const int*   x   = (const int*)d_in[0];
    const float* emb = (const float*)d_in[1];
    const float* Wg  = (const float*)d_in[2];
    const float* bg  = (const float*)d_in[3];
    const float* Wa  = (const float*)d_in[4];
    const float* va  = (const float*)d_in[5];
    const float* WV  = (const float*)d_in[6];
    const float* bV  = (const float*)d_in[7];
    float* out = (float*)d_out;

    char* ws = (char*)d_ws;
    size_t o = 0;
    auto alloc = [&](size_t bytes) { void* p = ws + o; o += (bytes + 255) & ~(size_t)255; return p; };
    f16*      e16   = (f16*)alloc((size_t)Sn * Bn * En * 2);        // 33.5 MB
    f16*      Wa_hi = (f16*)alloc((size_t)Hn * Hn * 2);             // 2 MB
    unsigned* h_pk  = (unsigned*)alloc((size_t)(Sn + 1) * Bn * Hn * 4); // 134.5 MB
    float*    energy= (float*)alloc((size_t)Bn * Sn * 4);
    float*    ctx   = (float*)alloc((size_t)Bn * Hn * 4);
    unsigned* bar   = (unsigned*)alloc(4096);
    // total ~170 MB

    hipMemsetAsync(h_pk, 0, (size_t)Bn * Hn * 4, stream);   // slot 0 = zeros
    hipMemsetAsync(energy, 0, (size_t)Bn * Sn * 4, stream);
    hipMemsetAsync(bar, 0, 4096, stream);

    gather_e_k<<<8192, 256, 0, stream>>>(x, emb, e16);
    split_wa_k<<<512, 256, 0, stream>>>(Wa, Wa_hi);

    lstm_persist_k<<<256, 256, 0, stream>>>(e16, Wg, bg, h_pk, bar);

    energy_k<<<512 * 8, 256, 0, stream>>>(h_pk, Wa_hi, va, energy);
    softctx_k<<<Bn, 256, 0, stream>>>(energy, x, h_pk, ctx);
    logits_k<<<Bn, 256, 0, stream>>>(ctx, WV, bV, out);
}

// Round 6
// 5795.527 us; speedup vs baseline: 1.3352x; 1.0158x over previous
//
#include <hip/hip_runtime.h>

// LSTM_36807869726767 — round 10: wave-granular barrier, contention-hardened.
// Round-9 bench died (container failed twice, no counters). Suspect: 1024
// global pollers at s_sleep(2) on ONE L3 line (8x round-4 poll pressure),
// racing the barrier fetch_adds on the same line -> pathological queueing.
// This round keeps the wave-granular experiment (single variable vs round 8
// remains sync granularity) but removes the hotspot:
//  - LDS mailbox relay: only wave0/lane0 polls global root (256 pollers,
//    round-4 proven level) and republishes to an LDS word; waves 1-3 spin on
//    LDS (broadcast ds_read, zero global traffic). Monotonic -> deadlock-free.
//  - s_sleep(4) (round-4 cadence), bail 1<<20 (worst case bounded <0.5s).
//  - everything else byte-identical to round 9 (zero syncthreads in loop,
//    per-wave vmcnt(0) drain + arrive, 64 wave-arrivals/group, 16 groups).
// B=64, S=512, E=512, H=1024, NCLS=10, PAD=0. All float I/O f32.

typedef _Float16 f16;
typedef __attribute__((ext_vector_type(8))) _Float16 f16x8;
typedef __attribute__((ext_vector_type(4))) float f32x4;

#define Bn 64
#define Sn 512
#define En 512
#define Hn 1024

// low16 of a|b pairs -> one dword (hi parts); high16 -> lo parts
#define PERM_HI 0x05040100u
#define PERM_LO 0x07060302u

__device__ __forceinline__ float fsig(float x) {
    return __builtin_amdgcn_rcpf(1.f + __expf(-x));
}
__device__ __forceinline__ float ftanh(float x) {
    return 2.f * __builtin_amdgcn_rcpf(1.f + __expf(-2.f * x)) - 1.f;
}

// ------------------------------------------------- gather e -> f16 [t][b][k]
__global__ __launch_bounds__(256) void gather_e_k(
    const int* __restrict__ x, const float* __restrict__ emb,
    f16* __restrict__ e16)
{
    size_t g = (size_t)blockIdx.x * 256 + threadIdx.x;
    int row = (int)(g >> 6);          // t*64 + b
    int ko  = (int)(g & 63) * 8;
    int t = row >> 6, b = row & 63;
    int tok = x[b * Sn + t];
    float4 a  = *(const float4*)&emb[(size_t)tok * En + ko];
    float4 a2 = *(const float4*)&emb[(size_t)tok * En + ko + 4];
    float v[8] = {a.x, a.y, a.z, a.w, a2.x, a2.y, a2.z, a2.w};
    f16x8 h;
    #pragma unroll
    for (int i = 0; i < 8; ++i) h[i] = (f16)v[i];
    *(f16x8*)&e16[(size_t)row * En + ko] = h;
}

// ------------------------------------------------------------- Wa f32 -> f16
__global__ __launch_bounds__(256) void split_wa_k(
    const float* __restrict__ Wa, f16* __restrict__ hi)
{
    size_t g = ((size_t)blockIdx.x * 256 + threadIdx.x) * 8;
    float4 a = *(const float4*)&Wa[g];
    float4 b = *(const float4*)&Wa[g + 4];
    float v[8] = {a.x, a.y, a.z, a.w, b.x, b.y, b.z, b.w};
    f16x8 h;
    #pragma unroll
    for (int i = 0; i < 8; ++i) h[i] = (f16)v[i];
    *(f16x8*)&hi[g] = h;
}

// ------------------------------------------- persistent LSTM recurrence
// 256 blocks x 256 thr (1 wave/SIMD, all CUs). Block bk owns h-dims
// d0=4*bk..d0+3 (16 gate rows). Wave w = 16 batch rows. h state: write-once
// slots h_pk[slot][b][k] u32 (hi|lo f16 packed); slot t = state entering
// step t; slot 0 zeroed; step t writes slot t+1 via relaxed agent-scope
// atomic stores (write-through; readers use normal cached loads of
// write-once lines). Barrier is WAVE-granular: 1024 waves, 16 groups of 64
// (16 blocks x 4 waves); root reaches 16t when all waves finished step t-1.
// Wave0 polls root and relays via LDS mailbox; waves 1-3 spin on LDS.
__global__ __launch_bounds__(256) void lstm_persist_k(
    const f16* __restrict__ e16,      // [512*64][512]
    const float* __restrict__ Wg,     // [4096][1536] f32
    const float* __restrict__ bg,     // [4096]
    unsigned* __restrict__ h_pk,      // [513][64][1024] u32
    unsigned* __restrict__ bar)       // [16*32] group counters + [512] root
{
    // k-major [kchunk][16 rows][8]: zero pad, conflict-free ds_read_b128
    __shared__ f16 Wse[64 * 16 * 8];    // 16 KB (e-part, k=0..511)
    __shared__ f16 Wsh[128 * 16 * 8];   // 32 KB (h-part hi, k=512..1535)
    __shared__ f16 Wsl[128 * 16 * 8];   // 32 KB (h-part lo)
    __shared__ unsigned mbox;           // root relay (monotonic)

    const int tid = threadIdx.x;
    const int bk  = blockIdx.x;     // 0..255
    const int d0  = bk * 4;

    if (tid == 0) mbox = 0;

    // ---- one-time: stage + split 16 weight rows (f32 -> f16 hi/lo), k-major
    {
        int n = tid >> 4, l16 = tid & 15;
        int j = (n >> 2) * 1024 + d0 + (n & 3);
        const float* src = Wg + (size_t)j * 1536;
        for (int k = l16 * 4; k < 1536; k += 64) {
            float4 v = *(const float4*)&src[k];
            float vv[4] = {v.x, v.y, v.z, v.w};
            #pragma unroll
            for (int i = 0; i < 4; ++i) {
                int kk = k + i;
                f16 hv = (f16)vv[i];
                f16 lv = (f16)(vv[i] - (float)hv);
                if (kk < 512) {
                    Wse[((kk >> 3) * 16 + n) * 8 + (kk & 7)] = hv;
                } else {
                    int kh = kk - 512;
                    int idx = ((kh >> 3) * 16 + n) * 8 + (kh & 7);
                    Wsh[idx] = hv;
                    Wsl[idx] = lv;
                }
            }
        }
    }
    __syncthreads();   // one-time only; no syncthreads inside the step loop

    const int lane = tid & 63;
    const int w    = tid >> 6;
    const int cl   = lane & 15;
    const int q    = lane >> 4;
    const int b    = w * 16 + cl;
    const int ko   = q * 8;
    const int co   = cl & 3;
    const int jcol = (cl >> 2) * 1024 + d0 + (cl & 3);
    const float bgv = bg[jcol];

    const int wbase = (q * 16 + cl) * 8;   // lane base into k-major LDS
    const f16* Wse_r = &Wse[wbase];
    const f16* Wsh_r = &Wsh[wbase];
    const f16* Wsl_r = &Wsl[wbase];

    unsigned* grp  = &bar[(bk >> 4) * 32];   // 16 groups x (16 blocks * 4 waves)
    unsigned* root = &bar[512];

    float cst[4] = {0.f, 0.f, 0.f, 0.f};
    int bail = 0;

    for (int t = 0; t < Sn; ++t) {
        // ---- e-part (independent of h) — runs while barrier settles
        const f16* Ae = e16 + ((size_t)t * 64 + b) * En + ko;
        f32x4 accE = {bgv, bgv, bgv, bgv};   // bias folded in
        #pragma unroll 4
        for (int ks = 0; ks < 16; ++ks) {
            f16x8 a  = *(const f16x8*)&Ae[ks * 32];
            f16x8 bb = *(const f16x8*)&Wse_r[ks * 512];
            accE = __builtin_amdgcn_mfma_f32_16x16x32_f16(a, bb, accE, 0, 0, 0);
        }

        // ---- per-wave wait for step t-1 (root >= 16*t)
        if (t > 0 && !bail) {
            unsigned tgt = 16u * (unsigned)t;
            long spins = 0;
            if (w == 0) {
                // wave0: lane0 polls global root, relays to LDS mailbox
                for (;;) {
                    unsigned v = 0;
                    if (lane == 0) {
                        v = __hip_atomic_load(root, __ATOMIC_RELAXED,
                                              __HIP_MEMORY_SCOPE_AGENT);
                        __hip_atomic_store(&mbox, v, __ATOMIC_RELAXED,
                                           __HIP_MEMORY_SCOPE_WORKGROUP);
                    }
                    v = __shfl(v, 0, 64);
                    if (v >= tgt) break;
                    __builtin_amdgcn_s_sleep(4);
                    if (++spins > (1L << 20)) { bail = 1; break; }
                }
            } else {
                // waves 1-3: spin on LDS mailbox (no global traffic)
                for (;;) {
                    unsigned v = __hip_atomic_load(&mbox, __ATOMIC_RELAXED,
                                                   __HIP_MEMORY_SCOPE_WORKGROUP);
                    if (v >= tgt) break;
                    __builtin_amdgcn_s_sleep(4);
                    if (++spins > (1L << 20)) { bail = 1; break; }
                }
            }
        }
        __builtin_amdgcn_fence(__ATOMIC_ACQUIRE, "workgroup"); // no buffer_inv
        __asm__ __volatile__("" ::: "memory");

        // ---- h-part: normal cached loads of write-once slot t (L2 dedups)
        const unsigned* Ap = h_pk + ((size_t)t * 64 + b) * Hn + ko;
        f32x4 acc1 = {0.f, 0.f, 0.f, 0.f};
        f32x4 acc2 = {0.f, 0.f, 0.f, 0.f};
        f32x4 acc3 = {0.f, 0.f, 0.f, 0.f};
        #pragma unroll 4
        for (int ks = 0; ks < 32; ++ks) {
            uint4 p0 = *(const uint4*)&Ap[ks * 32];
            uint4 p1 = *(const uint4*)&Ap[ks * 32 + 4];
            union { unsigned u[4]; f16x8 v; } Ah, Al;
            Ah.u[0] = __builtin_amdgcn_perm(p0.y, p0.x, PERM_HI);
            Ah.u[1] = __builtin_amdgcn_perm(p0.w, p0.z, PERM_HI);
            Ah.u[2] = __builtin_amdgcn_perm(p1.y, p1.x, PERM_HI);
            Ah.u[3] = __builtin_amdgcn_perm(p1.w, p1.z, PERM_HI);
            Al.u[0] = __builtin_amdgcn_perm(p0.y, p0.x, PERM_LO);
            Al.u[1] = __builtin_amdgcn_perm(p0.w, p0.z, PERM_LO);
            Al.u[2] = __builtin_amdgcn_perm(p1.y, p1.x, PERM_LO);
            Al.u[3] = __builtin_amdgcn_perm(p1.w, p1.z, PERM_LO);
            f16x8 bh = *(const f16x8*)&Wsh_r[ks * 512];
            f16x8 bl = *(const f16x8*)&Wsl_r[ks * 512];
            acc1 = __builtin_amdgcn_mfma_f32_16x16x32_f16(Ah.v, bh, acc1, 0, 0, 0);
            acc2 = __builtin_amdgcn_mfma_f32_16x16x32_f16(Ah.v, bl, acc2, 0, 0, 0);
            acc3 = __builtin_amdgcn_mfma_f32_16x16x32_f16(Al.v, bh, acc3, 0, 0, 0);
        }
        f32x4 acc;
        #pragma unroll
        for (int r = 0; r < 4; ++r)
            acc[r] = (accE[r] + acc1[r]) + (acc2[r] + acc3[r]);

        // ---- cell update. D: col=cl (gate jcol), row=q*4+r (batch w*16+q*4+r)
        #pragma unroll
        for (int r = 0; r < 4; ++r) {
            float av = acc[r];
            float iv = __shfl(av, (lane & 48) | co,      64);
            float fv = __shfl(av, (lane & 48) | 4 | co,  64);
            float gv = __shfl(av, (lane & 48) | 8 | co,  64);
            float ov = __shfl(av, (lane & 48) | 12 | co, 64);
            if (cl < 4) {
                int d  = d0 + co;
                int br = w * 16 + q * 4 + r;
                float i_ = fsig(iv);
                float f_ = fsig(fv);
                float g_ = ftanh(gv);
                float o_ = fsig(ov);
                float cn = f_ * cst[r] + i_ * g_;
                cst[r] = cn;
                float hn = o_ * ftanh(cn);
                f16 hh = (f16)hn;
                f16 hl = (f16)(hn - (float)hh);
                unsigned pkv = (unsigned)__builtin_bit_cast(unsigned short, hh)
                             | ((unsigned)__builtin_bit_cast(unsigned short, hl) << 16);
                // to coherence point (sc0 sc1), bypasses L2 -> L2 stays clean
                __hip_atomic_store(&h_pk[((size_t)(t + 1) * 64 + br) * Hn + d],
                                   pkv, __ATOMIC_RELAXED, __HIP_MEMORY_SCOPE_AGENT);
            }
        }

        // ---- per-wave arrive: drain own stores, then count this wave
        __asm__ __volatile__("s_waitcnt vmcnt(0)" ::: "memory");
        if (lane == 0) {
            unsigned prev = __hip_atomic_fetch_add(grp, 1u, __ATOMIC_RELAXED,
                                                   __HIP_MEMORY_SCOPE_AGENT);
            if ((prev & 63u) == 63u)   // 64th wave arrival of this step in group
                __hip_atomic_fetch_add(root, 1u, __ATOMIC_RELAXED,
                                       __HIP_MEMORY_SCOPE_AGENT);
        }
    }
}

// ---------------------------------------------------------------- energy GEMM
// rows r = t*64+b (h_pk linear row r+64); energy[r] += tanh(row.Wa[d]) * va[d]
__global__ __launch_bounds__(256) void energy_k(
    const unsigned* __restrict__ h_pk,  // [513*64][1024] u32
    const f16* __restrict__ Wa_hi,      // [H][H]
    const float* __restrict__ va,       // [H]
    float* __restrict__ energy)         // [B*S] (r-indexed), pre-zeroed
{
    __shared__ f16 Was[128][136];
    const int bid = blockIdx.x;
    const int rb = bid >> 3;
    const int nb = bid & 7;
    const int tid = threadIdx.x;
    const int lane = tid & 63, w = tid >> 6, cl = lane & 15, q = lane >> 4;
    const int r0 = rb * 64 + w * 16 + cl;

    f32x4 acc[8];
    #pragma unroll
    for (int i = 0; i < 8; ++i) acc[i] = (f32x4){0.f, 0.f, 0.f, 0.f};

    for (int kc = 0; kc < 8; ++kc) {
        __syncthreads();
        for (int i = tid; i < 128 * 16; i += 256) {
            int dd = i >> 4;
            int kv = (i & 15) * 8;
            *(f16x8*)&Was[dd][kv] =
                *(const f16x8*)&Wa_hi[(size_t)(nb * 128 + dd) * Hn + kc * 128 + kv];
        }
        __syncthreads();
        const unsigned* A = h_pk + (size_t)(r0 + 64) * Hn + kc * 128;
        #pragma unroll
        for (int ks = 0; ks < 4; ++ks) {
            uint4 p0 = *(const uint4*)&A[ks * 32 + q * 8];
            uint4 p1 = *(const uint4*)&A[ks * 32 + q * 8 + 4];
            union { unsigned u[4]; f16x8 v; } Ah;
            Ah.u[0] = __builtin_amdgcn_perm(p0.y, p0.x, PERM_HI);
            Ah.u[1] = __builtin_amdgcn_perm(p0.w, p0.z, PERM_HI);
            Ah.u[2] = __builtin_amdgcn_perm(p1.y, p1.x, PERM_HI);
            Ah.u[3] = __builtin_amdgcn_perm(p1.w, p1.z, PERM_HI);
            #pragma unroll
            for (int nt = 0; nt < 8; ++nt) {
                f16x8 bb = *(const f16x8*)&Was[nt * 16 + cl][ks * 32 + q * 8];
                acc[nt] = __builtin_amdgcn_mfma_f32_16x16x32_f16(Ah.v, bb, acc[nt], 0, 0, 0);
            }
        }
    }

    float rowsum[4] = {0.f, 0.f, 0.f, 0.f};
    #pragma unroll
    for (int nt = 0; nt < 8; ++nt) {
        float vv = va[nb * 128 + nt * 16 + cl];
        #pragma unroll
        for (int r = 0; r < 4; ++r)
            rowsum[r] += tanhf(acc[nt][r]) * vv;
    }
    #pragma unroll
    for (int m = 1; m < 16; m <<= 1)
        #pragma unroll
        for (int r = 0; r < 4; ++r)
            rowsum[r] += __shfl_xor(rowsum[r], m, 64);
    if (cl == 0) {
        #pragma unroll
        for (int r = 0; r < 4; ++r)
            atomicAdd(&energy[(size_t)rb * 64 + w * 16 + q * 4 + r], rowsum[r]);
    }
}

// ------------------------------------------------- masked softmax + context
// energy index for (b,s) = s*64 + b
__global__ __launch_bounds__(256) void softctx_k(
    const float* __restrict__ energy, const int* __restrict__ x,
    const unsigned* __restrict__ h_pk,
    float* __restrict__ context)   // [B][H]
{
    __shared__ float sm[512];
    __shared__ float red[256];
    const int b = blockIdx.x, tid = threadIdx.x;
    const int s0 = tid, s1 = tid + 256;
    float e0 = (x[b * Sn + s0] != 0) ? energy[s0 * 64 + b] : -1e10f;
    float e1 = (x[b * Sn + s1] != 0) ? energy[s1 * 64 + b] : -1e10f;
    red[tid] = fmaxf(e0, e1);
    __syncthreads();
    for (int st = 128; st > 0; st >>= 1) {
        if (tid < st) red[tid] = fmaxf(red[tid], red[tid + st]);
        __syncthreads();
    }
    float M = red[0];
    __syncthreads();
    float p0 = expf(e0 - M), p1 = expf(e1 - M);
    red[tid] = p0 + p1;
    __syncthreads();
    for (int st = 128; st > 0; st >>= 1) {
        if (tid < st) red[tid] += red[tid + st];
        __syncthreads();
    }
    float inv = 1.f / red[0];
    sm[s0] = p0 * inv; sm[s1] = p1 * inv;
    __syncthreads();

    const int d0v = tid * 4;
    float a0 = 0.f, a1 = 0.f, a2 = 0.f, a3 = 0.f;
    for (int s = 0; s < Sn; ++s) {
        float at = sm[s];
        uint4 pv = *(const uint4*)&h_pk[((size_t)(s + 1) * 64 + b) * Hn + d0v];
        union { unsigned u; _Float16 h[2]; } c0, c1, c2, c3;
        c0.u = pv.x; c1.u = pv.y; c2.u = pv.z; c3.u = pv.w;
        a0 += at * ((float)c0.h[0] + (float)c0.h[1]);
        a1 += at * ((float)c1.h[0] + (float)c1.h[1]);
        a2 += at * ((float)c2.h[0] + (float)c2.h[1]);
        a3 += at * ((float)c3.h[0] + (float)c3.h[1]);
    }
    float* cp = context + (size_t)b * Hn + d0v;
    cp[0] = a0; cp[1] = a1; cp[2] = a2; cp[3] = a3;
}

// ---------------------------------------------------------------- logits
__global__ __launch_bounds__(256) void logits_k(
    const float* __restrict__ context, const float* __restrict__ WV,
    const float* __restrict__ bV, float* __restrict__ out)
{
    __shared__ float red[10][257];
    const int b = blockIdx.x, tid = threadIdx.x;
    const int d0v = tid * 4;
    float4 cv = *(const float4*)&context[(size_t)b * Hn + d0v];
    #pragma unroll
    for (int cls = 0; cls < 10; ++cls) {
        float4 wv = *(const float4*)&WV[cls * Hn + d0v];
        red[cls][tid] = cv.x * wv.x + cv.y * wv.y + cv.z * wv.z + cv.w * wv.w;
    }
    __syncthreads();
    for (int st = 128; st > 0; st >>= 1) {
        if (tid < st)
            #pragma unroll
            for (int cls = 0; cls < 10; ++cls)
                red[cls][tid] += red[cls][tid + st];
        __syncthreads();
    }
    if (tid < 10) out[b * 10 + tid] = red[tid][0] + bV[tid];
}

// ---------------------------------------------------------------- launch
extern "C" void kernel_launch(void* const* d_in, const int* in_sizes, int n_in,
                              void* d_out, int out_size, void* d_ws, size_t ws_size,
                              hipStream_t stream)
{
    const int*   x   = (const int*)d_in[0];
    const float* emb = (const float*)d_in[1];
    const float* Wg  = (const float*)d_in[2];
    const float* bg  = (const float*)d_in[3];
    const float* Wa  = (const float*)d_in[4];
    const float* va  = (const float*)d_in[5];
    const float* WV  = (const float*)d_in[6];
    const float* bV  = (const float*)d_in[7];
    float* out = (float*)d_out;

    char* ws = (char*)d_ws;
    size_t o = 0;
    auto alloc = [&](size_t bytes) { void* p = ws + o; o += (bytes + 255) & ~(size_t)255; return p; };
    f16*      e16   = (f16*)alloc((size_t)Sn * Bn * En * 2);        // 33.5 MB
    f16*      Wa_hi = (f16*)alloc((size_t)Hn * Hn * 2);             // 2 MB
    unsigned* h_pk  = (unsigned*)alloc((size_t)(Sn + 1) * Bn * Hn * 4); // 134.5 MB
    float*    energy= (float*)alloc((size_t)Bn * Sn * 4);
    float*    ctx   = (float*)alloc((size_t)Bn * Hn * 4);
    unsigned* bar   = (unsigned*)alloc(4096);
    // total ~170 MB

    hipMemsetAsync(h_pk, 0, (size_t)Bn * Hn * 4, stream);   // slot 0 = zeros
    hipMemsetAsync(energy, 0, (size_t)Bn * Sn * 4, stream);
    hipMemsetAsync(bar, 0, 4096, stream);

    gather_e_k<<<8192, 256, 0, stream>>>(x, emb, e16);
    split_wa_k<<<512, 256, 0, stream>>>(Wa, Wa_hi);

    lstm_persist_k<<<256, 256, 0, stream>>>(e16, Wg, bg, h_pk, bar);

    energy_k<<<512 * 8, 256, 0, stream>>>(h_pk, Wa_hi, va, energy);
    softctx_k<<<Bn, 256, 0, stream>>>(energy, x, h_pk, ctx);
    logits_k<<<Bn, 256, 0, stream>>>(ctx, WV, bV, out);
}

// Round 9
// 4885.194 us; speedup vs baseline: 1.5840x; 1.1863x over previous
//
#include <hip/hip_runtime.h>

// LSTM_36807869726767 — round 13: single-f16 h experiment on the ROUND-8
// chassis (block barrier, tid0 poll, sleep(4), unroll 4 — passed 4 benches).
// Rounds 11/12 (same experiment on wave-granular chassis) killed containers
// twice; source audit finds no mechanism, so: keep the experiment, drop every
// element unique to the failed builds. Round 10 proved barrier granularity is
// perf-null -> nothing lost reverting it.
// Single-f16 h state vs round 8's hi/lo:
//  - h16[slot][b][k] plain f16; loads feed MFMA directly (zero v_perm);
//    h-loop = 32 x {16B load, ds_read_b128, 1 MFMA} (was 96 MFMA + perms).
//  - stores: pair-pack (d,d+1) via one shfl -> u32 agent-scope relaxed
//    stores (write-through, proven publish scheme); store count halves.
//  - LDS 82->49 KB (Wsl gone).
// Pre-commit: if passed=false (absmax), revert to hi/lo datapath, keep rest.
// B=64, S=512, E=512, H=1024, NCLS=10, PAD=0. All float I/O f32.

typedef _Float16 f16;
typedef __attribute__((ext_vector_type(8))) _Float16 f16x8;
typedef __attribute__((ext_vector_type(4))) _Float16 f16x4;
typedef __attribute__((ext_vector_type(4))) float f32x4;

#define Bn 64
#define Sn 512
#define En 512
#define Hn 1024

__device__ __forceinline__ float fsig(float x) {
    return __builtin_amdgcn_rcpf(1.f + __expf(-x));
}
__device__ __forceinline__ float ftanh(float x) {
    return 2.f * __builtin_amdgcn_rcpf(1.f + __expf(-2.f * x)) - 1.f;
}

// ------------------------------------------------- gather e -> f16 [t][b][k]
__global__ __launch_bounds__(256) void gather_e_k(
    const int* __restrict__ x, const float* __restrict__ emb,
    f16* __restrict__ e16)
{
    size_t g = (size_t)blockIdx.x * 256 + threadIdx.x;
    int row = (int)(g >> 6);          // t*64 + b
    int ko  = (int)(g & 63) * 8;
    int t = row >> 6, b = row & 63;
    int tok = x[b * Sn + t];
    float4 a  = *(const float4*)&emb[(size_t)tok * En + ko];
    float4 a2 = *(const float4*)&emb[(size_t)tok * En + ko + 4];
    float v[8] = {a.x, a.y, a.z, a.w, a2.x, a2.y, a2.z, a2.w};
    f16x8 h;
    #pragma unroll
    for (int i = 0; i < 8; ++i) h[i] = (f16)v[i];
    *(f16x8*)&e16[(size_t)row * En + ko] = h;
}

// ------------------------------------------------------------- Wa f32 -> f16
__global__ __launch_bounds__(256) void split_wa_k(
    const float* __restrict__ Wa, f16* __restrict__ hi)
{
    size_t g = ((size_t)blockIdx.x * 256 + threadIdx.x) * 8;
    float4 a = *(const float4*)&Wa[g];
    float4 b = *(const float4*)&Wa[g + 4];
    float v[8] = {a.x, a.y, a.z, a.w, b.x, b.y, b.z, b.w};
    f16x8 h;
    #pragma unroll
    for (int i = 0; i < 8; ++i) h[i] = (f16)v[i];
    *(f16x8*)&hi[g] = h;
}

// ------------------------------------------- persistent LSTM recurrence
// 256 blocks x 256 thr (1 wave/SIMD, all CUs). Block bk owns h-dims
// d0=4*bk..d0+3 (16 gate rows). Wave w = 16 batch rows. h state: write-once
// slots h16[slot][b][k] f16; slot t = state entering step t; slot 0 zeroed;
// step t writes slot t+1 via relaxed agent-scope u32 stores (two f16 packed;
// write-through to coherence point; readers use normal cached loads of
// write-once lines -> no stale data, no fences needed).
// Barrier: round-8 block-level (tid0 polls root, __syncthreads, tid0 arrive).
__global__ __launch_bounds__(256) void lstm_persist_k(
    const f16* __restrict__ e16,      // [512*64][512]
    const float* __restrict__ Wg,     // [4096][1536] f32
    const float* __restrict__ bg,     // [4096]
    f16* __restrict__ h16,            // [513][64][1024] f16
    unsigned* __restrict__ bar)       // [16*32] group counters + [512] root
{
    // k-major [kchunk][16 rows][8]: zero pad, conflict-free ds_read_b128
    __shared__ f16 Wse[64 * 16 * 8];    // 16 KB (e-part, k=0..511)
    __shared__ f16 Wsh[128 * 16 * 8];   // 32 KB (h-part, k=512..1535)

    const int tid = threadIdx.x;
    const int bk  = blockIdx.x;     // 0..255
    const int d0  = bk * 4;

    // ---- one-time: stage 16 weight rows (f32 -> f16), k-major
    {
        int n = tid >> 4, l16 = tid & 15;
        int j = (n >> 2) * 1024 + d0 + (n & 3);
        const float* src = Wg + (size_t)j * 1536;
        for (int k = l16 * 4; k < 1536; k += 64) {
            float4 v = *(const float4*)&src[k];
            float vv[4] = {v.x, v.y, v.z, v.w};
            #pragma unroll
            for (int i = 0; i < 4; ++i) {
                int kk = k + i;
                f16 hv = (f16)vv[i];
                if (kk < 512) {
                    Wse[((kk >> 3) * 16 + n) * 8 + (kk & 7)] = hv;
                } else {
                    int kh = kk - 512;
                    Wsh[((kh >> 3) * 16 + n) * 8 + (kh & 7)] = hv;
                }
            }
        }
    }
    __syncthreads();

    const int lane = tid & 63;
    const int w    = tid >> 6;
    const int cl   = lane & 15;
    const int q    = lane >> 4;
    const int b    = w * 16 + cl;
    const int ko   = q * 8;
    const int co   = cl & 3;
    const int jcol = (cl >> 2) * 1024 + d0 + (cl & 3);
    const float bgv = bg[jcol];

    const int wbase = (q * 16 + cl) * 8;   // lane base into k-major LDS
    const f16* Wse_r = &Wse[wbase];
    const f16* Wsh_r = &Wsh[wbase];

    unsigned* grp  = &bar[(bk >> 4) * 32];
    unsigned* root = &bar[512];

    float cst[4] = {0.f, 0.f, 0.f, 0.f};
    int bail = 0;

    for (int t = 0; t < Sn; ++t) {
        // ---- e-part (independent of h) — runs while barrier settles
        const f16* Ae = e16 + ((size_t)t * 64 + b) * En + ko;
        f32x4 accE = {bgv, bgv, bgv, bgv};   // bias folded in
        #pragma unroll 4
        for (int ks = 0; ks < 16; ++ks) {
            f16x8 a  = *(const f16x8*)&Ae[ks * 32];
            f16x8 bb = *(const f16x8*)&Wse_r[ks * 512];
            accE = __builtin_amdgcn_mfma_f32_16x16x32_f16(a, bb, accE, 0, 0, 0);
        }

        // ---- wait for step t-1 (root >= 16*t); relaxed spin, no acquire
        if (tid == 0 && t > 0 && !bail) {
            unsigned tgt = 16u * (unsigned)t;
            long spins = 0;
            while (__hip_atomic_load(root, __ATOMIC_RELAXED,
                                     __HIP_MEMORY_SCOPE_AGENT) < tgt) {
                __builtin_amdgcn_s_sleep(4);
                if (++spins > (1L << 24)) { bail = 1; break; }
            }
        }
        __syncthreads();
        __builtin_amdgcn_fence(__ATOMIC_ACQUIRE, "workgroup"); // no buffer_inv
        __asm__ __volatile__("" ::: "memory");

        // ---- h-part: normal cached loads of write-once slot t (L2 dedups);
        // f16 fragments feed MFMA directly (no unpack)
        const f16* Ah = h16 + ((size_t)t * 64 + b) * Hn + ko;
        f32x4 acc1 = {0.f, 0.f, 0.f, 0.f};
        #pragma unroll 4
        for (int ks = 0; ks < 32; ++ks) {
            f16x8 ah = *(const f16x8*)&Ah[ks * 32];
            f16x8 bh = *(const f16x8*)&Wsh_r[ks * 512];
            acc1 = __builtin_amdgcn_mfma_f32_16x16x32_f16(ah, bh, acc1, 0, 0, 0);
        }
        f32x4 acc;
        #pragma unroll
        for (int r = 0; r < 4; ++r)
            acc[r] = accE[r] + acc1[r];

        // ---- cell update. D: col=cl (gate jcol), row=q*4+r (batch w*16+q*4+r)
        #pragma unroll
        for (int r = 0; r < 4; ++r) {
            float av = acc[r];
            float iv = __shfl(av, (lane & 48) | co,      64);
            float fv = __shfl(av, (lane & 48) | 4 | co,  64);
            float gv = __shfl(av, (lane & 48) | 8 | co,  64);
            float ov = __shfl(av, (lane & 48) | 12 | co, 64);
            if (cl < 4) {
                float i_ = fsig(iv);
                float f_ = fsig(fv);
                float g_ = ftanh(gv);
                float o_ = fsig(ov);
                float cn = f_ * cst[r] + i_ * g_;
                cst[r] = cn;
                float hn = o_ * ftanh(cn);
                unsigned my = (unsigned)__builtin_bit_cast(unsigned short, (f16)hn);
                // pair-pack with neighbor lane (cl pairs (0,1),(2,3) both
                // inside the cl<4 region -> all shfl participants active)
                unsigned nb = __shfl(my, lane ^ 1, 64);
                if ((co & 1) == 0) {
                    unsigned pk = my | (nb << 16);   // dims (d0+co, d0+co+1)
                    int br = w * 16 + q * 4 + r;
                    unsigned* dst = (unsigned*)&h16[((size_t)(t + 1) * 64 + br) * Hn + d0 + co];
                    // to coherence point (sc0 sc1), bypasses L2 -> L2 clean
                    __hip_atomic_store(dst, pk, __ATOMIC_RELAXED,
                                       __HIP_MEMORY_SCOPE_AGENT);
                }
            }
        }

        // ---- arrive: __syncthreads drains vmcnt(0) per wave (stores acked)
        __syncthreads();
        __asm__ __volatile__("" ::: "memory");
        if (tid == 0) {
            unsigned prev = __hip_atomic_fetch_add(grp, 1u, __ATOMIC_RELAXED,
                                                   __HIP_MEMORY_SCOPE_AGENT);
            if ((prev & 15u) == 15u)   // 16th arrival of this step in group
                __hip_atomic_fetch_add(root, 1u, __ATOMIC_RELAXED,
                                       __HIP_MEMORY_SCOPE_AGENT);
        }
    }
}

// ---------------------------------------------------------------- energy GEMM
// rows r = t*64+b (h16 linear row r+64); energy[r] += tanh(row.Wa[d]) * va[d]
__global__ __launch_bounds__(256) void energy_k(
    const f16* __restrict__ h16,        // [513*64][1024] f16
    const f16* __restrict__ Wa_hi,      // [H][H]
    const float* __restrict__ va,       // [H]
    float* __restrict__ energy)         // [B*S] (r-indexed), pre-zeroed
{
    __shared__ f16 Was[128][136];
    const int bid = blockIdx.x;
    const int rb = bid >> 3;
    const int nb = bid & 7;
    const int tid = threadIdx.x;
    const int lane = tid & 63, w = tid >> 6, cl = lane & 15, q = lane >> 4;
    const int r0 = rb * 64 + w * 16 + cl;

    f32x4 acc[8];
    #pragma unroll
    for (int i = 0; i < 8; ++i) acc[i] = (f32x4){0.f, 0.f, 0.f, 0.f};

    for (int kc = 0; kc < 8; ++kc) {
        __syncthreads();
        for (int i = tid; i < 128 * 16; i += 256) {
            int dd = i >> 4;
            int kv = (i & 15) * 8;
            *(f16x8*)&Was[dd][kv] =
                *(const f16x8*)&Wa_hi[(size_t)(nb * 128 + dd) * Hn + kc * 128 + kv];
        }
        __syncthreads();
        const f16* A = h16 + (size_t)(r0 + 64) * Hn + kc * 128;
        #pragma unroll
        for (int ks = 0; ks < 4; ++ks) {
            f16x8 ah = *(const f16x8*)&A[ks * 32 + q * 8];
            #pragma unroll
            for (int nt = 0; nt < 8; ++nt) {
                f16x8 bb = *(const f16x8*)&Was[nt * 16 + cl][ks * 32 + q * 8];
                acc[nt] = __builtin_amdgcn_mfma_f32_16x16x32_f16(ah, bb, acc[nt], 0, 0, 0);
            }
        }
    }

    float rowsum[4] = {0.f, 0.f, 0.f, 0.f};
    #pragma unroll
    for (int nt = 0; nt < 8; ++nt) {
        float vv = va[nb * 128 + nt * 16 + cl];
        #pragma unroll
        for (int r = 0; r < 4; ++r)
            rowsum[r] += tanhf(acc[nt][r]) * vv;
    }
    #pragma unroll
    for (int m = 1; m < 16; m <<= 1)
        #pragma unroll
        for (int r = 0; r < 4; ++r)
            rowsum[r] += __shfl_xor(rowsum[r], m, 64);
    if (cl == 0) {
        #pragma unroll
        for (int r = 0; r < 4; ++r)
            atomicAdd(&energy[(size_t)rb * 64 + w * 16 + q * 4 + r], rowsum[r]);
    }
}

// ------------------------------------------------- masked softmax + context
// energy index for (b,s) = s*64 + b
__global__ __launch_bounds__(256) void softctx_k(
    const float* __restrict__ energy, const int* __restrict__ x,
    const f16* __restrict__ h16,
    float* __restrict__ context)   // [B][H]
{
    __shared__ float sm[512];
    __shared__ float red[256];
    const int b = blockIdx.x, tid = threadIdx.x;
    const int s0 = tid, s1 = tid + 256;
    float e0 = (x[b * Sn + s0] != 0) ? energy[s0 * 64 + b] : -1e10f;
    float e1 = (x[b * Sn + s1] != 0) ? energy[s1 * 64 + b] : -1e10f;
    red[tid] = fmaxf(e0, e1);
    __syncthreads();
    for (int st = 128; st > 0; st >>= 1) {
        if (tid < st) red[tid] = fmaxf(red[tid], red[tid + st]);
        __syncthreads();
    }
    float M = red[0];
    __syncthreads();
    float p0 = expf(e0 - M), p1 = expf(e1 - M);
    red[tid] = p0 + p1;
    __syncthreads();
    for (int st = 128; st > 0; st >>= 1) {
        if (tid < st) red[tid] += red[tid + st];
        __syncthreads();
    }
    float inv = 1.f / red[0];
    sm[s0] = p0 * inv; sm[s1] = p1 * inv;
    __syncthreads();

    const int d0v = tid * 4;
    float a0 = 0.f, a1 = 0.f, a2 = 0.f, a3 = 0.f;
    for (int s = 0; s < Sn; ++s) {
        float at = sm[s];
        f16x4 hv = *(const f16x4*)&h16[((size_t)(s + 1) * 64 + b) * Hn + d0v];
        a0 += at * (float)hv[0];
        a1 += at * (float)hv[1];
        a2 += at * (float)hv[2];
        a3 += at * (float)hv[3];
    }
    float* cp = context + (size_t)b * Hn + d0v;
    cp[0] = a0; cp[1] = a1; cp[2] = a2; cp[3] = a3;
}

// ---------------------------------------------------------------- logits
__global__ __launch_bounds__(256) void logits_k(
    const float* __restrict__ context, const float* __restrict__ WV,
    const float* __restrict__ bV, float* __restrict__ out)
{
    __shared__ float red[10][257];
    const int b = blockIdx.x, tid = threadIdx.x;
    const int d0v = tid * 4;
    float4 cv = *(const float4*)&context[(size_t)b * Hn + d0v];
    #pragma unroll
    for (int cls = 0; cls < 10; ++cls) {
        float4 wv = *(const float4*)&WV[cls * Hn + d0v];
        red[cls][tid] = cv.x * wv.x + cv.y * wv.y + cv.z * wv.z + cv.w * wv.w;
    }
    __syncthreads();
    for (int st = 128; st > 0; st >>= 1) {
        if (tid < st)
            #pragma unroll
            for (int cls = 0; cls < 10; ++cls)
                red[cls][tid] += red[cls][tid + st];
        __syncthreads();
    }
    if (tid < 10) out[b * 10 + tid] = red[tid][0] + bV[tid];
}

// ---------------------------------------------------------------- launch
extern "C" void kernel_launch(void* const* d_in, const int* in_sizes, int n_in,
                              void* d_out, int out_size, void* d_ws, size_t ws_size,
                              hipStream_t stream)
{
    const int*   x   = (const int*)d_in[0];
    const float* emb = (const float*)d_in[1];
    const float* Wg  = (const float*)d_in[2];
    const float* bg  = (const float*)d_in[3];
    const float* Wa  = (const float*)d_in[4];
    const float* va  = (const float*)d_in[5];
    const float* WV  = (const float*)d_in[6];
    const float* bV  = (const float*)d_in[7];
    float* out = (float*)d_out;

    char* ws = (char*)d_ws;
    size_t o = 0;
    auto alloc = [&](size_t bytes) { void* p = ws + o; o += (bytes + 255) & ~(size_t)255; return p; };
    f16*      e16   = (f16*)alloc((size_t)Sn * Bn * En * 2);        // 33.5 MB
    f16*      Wa_hi = (f16*)alloc((size_t)Hn * Hn * 2);             // 2 MB
    f16*      h16   = (f16*)alloc((size_t)(Sn + 1) * Bn * Hn * 2);  // 67.2 MB
    float*    energy= (float*)alloc((size_t)Bn * Sn * 4);
    float*    ctx   = (float*)alloc((size_t)Bn * Hn * 4);
    unsigned* bar   = (unsigned*)alloc(4096);
    // total ~103 MB

    hipMemsetAsync(h16, 0, (size_t)Bn * Hn * 2, stream);    // slot 0 = zeros
    hipMemsetAsync(energy, 0, (size_t)Bn * Sn * 4, stream);
    hipMemsetAsync(bar, 0, 4096, stream);

    gather_e_k<<<8192, 256, 0, stream>>>(x, emb, e16);
    split_wa_k<<<512, 256, 0, stream>>>(Wa, Wa_hi);

    lstm_persist_k<<<256, 256, 0, stream>>>(e16, Wg, bg, h16, bar);

    energy_k<<<512 * 8, 256, 0, stream>>>(h16, Wa_hi, va, energy);
    softctx_k<<<Bn, 256, 0, stream>>>(energy, x, h16, ctx);
    logits_k<<<Bn, 256, 0, stream>>>(ctx, WV, bV, out);
}

// Round 10
// 3903.046 us; speedup vs baseline: 1.9826x; 1.2516x over previous
//
#include <hip/hip_runtime.h>

// LSTM_36807869726767 — round 14: register burst-load + e software pipeline.
// Round-13 post-mortem: single-f16 h landed (−18%, counters matched, absmax
// UNCHANGED -> lo-correction was pure overhead). Remaining 21.4K cyc/step:
// publish chain ~3K + h-load latency exposure (unroll-4 loop = 8 serialized
// L3 round trips at 1 wave/SIMD, VGPR only 68/256). This round:
//  - h-phase: burst-load all 32 A-frags into ha[32] (static idx, 128 VGPR),
//    then 32 MFMAs consume in load order -> 1 latency + BW, not 8 trips.
//  - e-pipeline: issue t+1's 16 e-loads right behind the h burst; e-MFMAs
//    at top of t+1 consume regs loaded a full step earlier (e latency off
//    the straggler critical path).
//  - acc1 seeded from accE (mfma C-in chaining); s_sleep(1) (proven r7).
// Barrier/stores/layout byte-identical to round 13 (passed, 4564us).
// B=64, S=512, E=512, H=1024, NCLS=10, PAD=0. All float I/O f32.

typedef _Float16 f16;
typedef __attribute__((ext_vector_type(8))) _Float16 f16x8;
typedef __attribute__((ext_vector_type(4))) _Float16 f16x4;
typedef __attribute__((ext_vector_type(4))) float f32x4;

#define Bn 64
#define Sn 512
#define En 512
#define Hn 1024

__device__ __forceinline__ float fsig(float x) {
    return __builtin_amdgcn_rcpf(1.f + __expf(-x));
}
__device__ __forceinline__ float ftanh(float x) {
    return 2.f * __builtin_amdgcn_rcpf(1.f + __expf(-2.f * x)) - 1.f;
}

// ------------------------------------------------- gather e -> f16 [t][b][k]
__global__ __launch_bounds__(256) void gather_e_k(
    const int* __restrict__ x, const float* __restrict__ emb,
    f16* __restrict__ e16)
{
    size_t g = (size_t)blockIdx.x * 256 + threadIdx.x;
    int row = (int)(g >> 6);          // t*64 + b
    int ko  = (int)(g & 63) * 8;
    int t = row >> 6, b = row & 63;
    int tok = x[b * Sn + t];
    float4 a  = *(const float4*)&emb[(size_t)tok * En + ko];
    float4 a2 = *(const float4*)&emb[(size_t)tok * En + ko + 4];
    float v[8] = {a.x, a.y, a.z, a.w, a2.x, a2.y, a2.z, a2.w};
    f16x8 h;
    #pragma unroll
    for (int i = 0; i < 8; ++i) h[i] = (f16)v[i];
    *(f16x8*)&e16[(size_t)row * En + ko] = h;
}

// ------------------------------------------------------------- Wa f32 -> f16
__global__ __launch_bounds__(256) void split_wa_k(
    const float* __restrict__ Wa, f16* __restrict__ hi)
{
    size_t g = ((size_t)blockIdx.x * 256 + threadIdx.x) * 8;
    float4 a = *(const float4*)&Wa[g];
    float4 b = *(const float4*)&Wa[g + 4];
    float v[8] = {a.x, a.y, a.z, a.w, b.x, b.y, b.z, b.w};
    f16x8 h;
    #pragma unroll
    for (int i = 0; i < 8; ++i) h[i] = (f16)v[i];
    *(f16x8*)&hi[g] = h;
}

// ------------------------------------------- persistent LSTM recurrence
// 256 blocks x 256 thr (1 wave/SIMD, all CUs). Block bk owns h-dims
// d0=4*bk..d0+3 (16 gate rows). Wave w = 16 batch rows. h state: write-once
// slots h16[slot][b][k] f16; slot t = state entering step t; slot 0 zeroed;
// step t writes slot t+1 via relaxed agent-scope u32 stores (two f16 packed;
// write-through to coherence point; readers use normal cached loads of
// write-once lines -> no stale data, no fences needed).
// Barrier: round-8 block-level (tid0 polls root, __syncthreads, tid0 arrive).
__global__ __launch_bounds__(256) void lstm_persist_k(
    const f16* __restrict__ e16,      // [512*64][512]
    const float* __restrict__ Wg,     // [4096][1536] f32
    const float* __restrict__ bg,     // [4096]
    f16* __restrict__ h16,            // [513][64][1024] f16
    unsigned* __restrict__ bar)       // [16*32] group counters + [512] root
{
    // k-major [kchunk][16 rows][8]: zero pad, conflict-free ds_read_b128
    __shared__ f16 Wse[64 * 16 * 8];    // 16 KB (e-part, k=0..511)
    __shared__ f16 Wsh[128 * 16 * 8];   // 32 KB (h-part, k=512..1535)

    const int tid = threadIdx.x;
    const int bk  = blockIdx.x;     // 0..255
    const int d0  = bk * 4;

    // ---- one-time: stage 16 weight rows (f32 -> f16), k-major
    {
        int n = tid >> 4, l16 = tid & 15;
        int j = (n >> 2) * 1024 + d0 + (n & 3);
        const float* src = Wg + (size_t)j * 1536;
        for (int k = l16 * 4; k < 1536; k += 64) {
            float4 v = *(const float4*)&src[k];
            float vv[4] = {v.x, v.y, v.z, v.w};
            #pragma unroll
            for (int i = 0; i < 4; ++i) {
                int kk = k + i;
                f16 hv = (f16)vv[i];
                if (kk < 512) {
                    Wse[((kk >> 3) * 16 + n) * 8 + (kk & 7)] = hv;
                } else {
                    int kh = kk - 512;
                    Wsh[((kh >> 3) * 16 + n) * 8 + (kh & 7)] = hv;
                }
            }
        }
    }
    __syncthreads();

    const int lane = tid & 63;
    const int w    = tid >> 6;
    const int cl   = lane & 15;
    const int q    = lane >> 4;
    const int b    = w * 16 + cl;
    const int ko   = q * 8;
    const int co   = cl & 3;
    const int jcol = (cl >> 2) * 1024 + d0 + (cl & 3);
    const float bgv = bg[jcol];

    const int wbase = (q * 16 + cl) * 8;   // lane base into k-major LDS
    const f16* Wse_r = &Wse[wbase];
    const f16* Wsh_r = &Wsh[wbase];

    unsigned* grp  = &bar[(bk >> 4) * 32];
    unsigned* root = &bar[512];

    float cst[4] = {0.f, 0.f, 0.f, 0.f};
    int bail = 0;

    // ---- e software pipeline: prime ea with step 0's fragments
    f16x8 ea[16];
    {
        const f16* Ae0 = e16 + (size_t)b * En + ko;
        #pragma unroll
        for (int ks = 0; ks < 16; ++ks)
            ea[ks] = *(const f16x8*)&Ae0[ks * 32];
    }

    for (int t = 0; t < Sn; ++t) {
        // ---- e-part MFMAs from registers loaded one step ago
        f32x4 accE = {bgv, bgv, bgv, bgv};   // bias folded in
        #pragma unroll
        for (int ks = 0; ks < 16; ++ks) {
            f16x8 bb = *(const f16x8*)&Wse_r[ks * 512];
            accE = __builtin_amdgcn_mfma_f32_16x16x32_f16(ea[ks], bb, accE, 0, 0, 0);
        }

        // ---- wait for step t-1 (root >= 16*t); relaxed spin, no acquire
        if (tid == 0 && t > 0 && !bail) {
            unsigned tgt = 16u * (unsigned)t;
            long spins = 0;
            while (__hip_atomic_load(root, __ATOMIC_RELAXED,
                                     __HIP_MEMORY_SCOPE_AGENT) < tgt) {
                __builtin_amdgcn_s_sleep(1);
                if (++spins > (1L << 24)) { bail = 1; break; }
            }
        }
        __syncthreads();
        __builtin_amdgcn_fence(__ATOMIC_ACQUIRE, "workgroup"); // no buffer_inv
        __asm__ __volatile__("" ::: "memory");

        // ---- h-part: burst-issue all 32 A-frag loads (write-once slot t),
        // then next step's e-loads behind them; MFMAs consume in load order
        const f16* Ah = h16 + ((size_t)t * 64 + b) * Hn + ko;
        f16x8 ha[32];
        #pragma unroll
        for (int ks = 0; ks < 32; ++ks)
            ha[ks] = *(const f16x8*)&Ah[ks * 32];

        {
            int tn = (t + 1) & 511;   // harmless wrap on last iter
            const f16* Aen = e16 + ((size_t)tn * 64 + b) * En + ko;
            #pragma unroll
            for (int ks = 0; ks < 16; ++ks)
                ea[ks] = *(const f16x8*)&Aen[ks * 32];
        }

        f32x4 acc = accE;   // C-in chaining
        #pragma unroll
        for (int ks = 0; ks < 32; ++ks) {
            f16x8 bh = *(const f16x8*)&Wsh_r[ks * 512];
            acc = __builtin_amdgcn_mfma_f32_16x16x32_f16(ha[ks], bh, acc, 0, 0, 0);
        }

        // ---- cell update. D: col=cl (gate jcol), row=q*4+r (batch w*16+q*4+r)
        #pragma unroll
        for (int r = 0; r < 4; ++r) {
            float av = acc[r];
            float iv = __shfl(av, (lane & 48) | co,      64);
            float fv = __shfl(av, (lane & 48) | 4 | co,  64);
            float gv = __shfl(av, (lane & 48) | 8 | co,  64);
            float ov = __shfl(av, (lane & 48) | 12 | co, 64);
            if (cl < 4) {
                float i_ = fsig(iv);
                float f_ = fsig(fv);
                float g_ = ftanh(gv);
                float o_ = fsig(ov);
                float cn = f_ * cst[r] + i_ * g_;
                cst[r] = cn;
                float hn = o_ * ftanh(cn);
                unsigned my = (unsigned)__builtin_bit_cast(unsigned short, (f16)hn);
                // pair-pack with neighbor lane (cl pairs (0,1),(2,3) both
                // inside the cl<4 region -> all shfl participants active)
                unsigned nb = __shfl(my, lane ^ 1, 64);
                if ((co & 1) == 0) {
                    unsigned pk = my | (nb << 16);   // dims (d0+co, d0+co+1)
                    int br = w * 16 + q * 4 + r;
                    unsigned* dst = (unsigned*)&h16[((size_t)(t + 1) * 64 + br) * Hn + d0 + co];
                    // to coherence point (sc0 sc1), bypasses L2 -> L2 clean
                    __hip_atomic_store(dst, pk, __ATOMIC_RELAXED,
                                       __HIP_MEMORY_SCOPE_AGENT);
                }
            }
        }

        // ---- arrive: __syncthreads drains vmcnt(0) per wave (stores acked)
        __syncthreads();
        __asm__ __volatile__("" ::: "memory");
        if (tid == 0) {
            unsigned prev = __hip_atomic_fetch_add(grp, 1u, __ATOMIC_RELAXED,
                                                   __HIP_MEMORY_SCOPE_AGENT);
            if ((prev & 15u) == 15u)   // 16th arrival of this step in group
                __hip_atomic_fetch_add(root, 1u, __ATOMIC_RELAXED,
                                       __HIP_MEMORY_SCOPE_AGENT);
        }
    }
}

// ---------------------------------------------------------------- energy GEMM
// rows r = t*64+b (h16 linear row r+64); energy[r] += tanh(row.Wa[d]) * va[d]
__global__ __launch_bounds__(256) void energy_k(
    const f16* __restrict__ h16,        // [513*64][1024] f16
    const f16* __restrict__ Wa_hi,      // [H][H]
    const float* __restrict__ va,       // [H]
    float* __restrict__ energy)         // [B*S] (r-indexed), pre-zeroed
{
    __shared__ f16 Was[128][136];
    const int bid = blockIdx.x;
    const int rb = bid >> 3;
    const int nb = bid & 7;
    const int tid = threadIdx.x;
    const int lane = tid & 63, w = tid >> 6, cl = lane & 15, q = lane >> 4;
    const int r0 = rb * 64 + w * 16 + cl;

    f32x4 acc[8];
    #pragma unroll
    for (int i = 0; i < 8; ++i) acc[i] = (f32x4){0.f, 0.f, 0.f, 0.f};

    for (int kc = 0; kc < 8; ++kc) {
        __syncthreads();
        for (int i = tid; i < 128 * 16; i += 256) {
            int dd = i >> 4;
            int kv = (i & 15) * 8;
            *(f16x8*)&Was[dd][kv] =
                *(const f16x8*)&Wa_hi[(size_t)(nb * 128 + dd) * Hn + kc * 128 + kv];
        }
        __syncthreads();
        const f16* A = h16 + (size_t)(r0 + 64) * Hn + kc * 128;
        #pragma unroll
        for (int ks = 0; ks < 4; ++ks) {
            f16x8 ah = *(const f16x8*)&A[ks * 32 + q * 8];
            #pragma unroll
            for (int nt = 0; nt < 8; ++nt) {
                f16x8 bb = *(const f16x8*)&Was[nt * 16 + cl][ks * 32 + q * 8];
                acc[nt] = __builtin_amdgcn_mfma_f32_16x16x32_f16(ah, bb, acc[nt], 0, 0, 0);
            }
        }
    }

    float rowsum[4] = {0.f, 0.f, 0.f, 0.f};
    #pragma unroll
    for (int nt = 0; nt < 8; ++nt) {
        float vv = va[nb * 128 + nt * 16 + cl];
        #pragma unroll
        for (int r = 0; r < 4; ++r)
            rowsum[r] += tanhf(acc[nt][r]) * vv;
    }
    #pragma unroll
    for (int m = 1; m < 16; m <<= 1)
        #pragma unroll
        for (int r = 0; r < 4; ++r)
            rowsum[r] += __shfl_xor(rowsum[r], m, 64);
    if (cl == 0) {
        #pragma unroll
        for (int r = 0; r < 4; ++r)
            atomicAdd(&energy[(size_t)rb * 64 + w * 16 + q * 4 + r], rowsum[r]);
    }
}

// ------------------------------------------------- masked softmax + context
// energy index for (b,s) = s*64 + b
__global__ __launch_bounds__(256) void softctx_k(
    const float* __restrict__ energy, const int* __restrict__ x,
    const f16* __restrict__ h16,
    float* __restrict__ context)   // [B][H]
{
    __shared__ float sm[512];
    __shared__ float red[256];
    const int b = blockIdx.x, tid = threadIdx.x;
    const int s0 = tid, s1 = tid + 256;
    float e0 = (x[b * Sn + s0] != 0) ? energy[s0 * 64 + b] : -1e10f;
    float e1 = (x[b * Sn + s1] != 0) ? energy[s1 * 64 + b] : -1e10f;
    red[tid] = fmaxf(e0, e1);
    __syncthreads();
    for (int st = 128; st > 0; st >>= 1) {
        if (tid < st) red[tid] = fmaxf(red[tid], red[tid + st]);
        __syncthreads();
    }
    float M = red[0];
    __syncthreads();
    float p0 = expf(e0 - M), p1 = expf(e1 - M);
    red[tid] = p0 + p1;
    __syncthreads();
    for (int st = 128; st > 0; st >>= 1) {
        if (tid < st) red[tid] += red[tid + st];
        __syncthreads();
    }
    float inv = 1.f / red[0];
    sm[s0] = p0 * inv; sm[s1] = p1 * inv;
    __syncthreads();

    const int d0v = tid * 4;
    float a0 = 0.f, a1 = 0.f, a2 = 0.f, a3 = 0.f;
    for (int s = 0; s < Sn; ++s) {
        float at = sm[s];
        f16x4 hv = *(const f16x4*)&h16[((size_t)(s + 1) * 64 + b) * Hn + d0v];
        a0 += at * (float)hv[0];
        a1 += at * (float)hv[1];
        a2 += at * (float)hv[2];
        a3 += at * (float)hv[3];
    }
    float* cp = context + (size_t)b * Hn + d0v;
    cp[0] = a0; cp[1] = a1; cp[2] = a2; cp[3] = a3;
}

// ---------------------------------------------------------------- logits
__global__ __launch_bounds__(256) void logits_k(
    const float* __restrict__ context, const float* __restrict__ WV,
    const float* __restrict__ bV, float* __restrict__ out)
{
    __shared__ float red[10][257];
    const int b = blockIdx.x, tid = threadIdx.x;
    const int d0v = tid * 4;
    float4 cv = *(const float4*)&context[(size_t)b * Hn + d0v];
    #pragma unroll
    for (int cls = 0; cls < 10; ++cls) {
        float4 wv = *(const float4*)&WV[cls * Hn + d0v];
        red[cls][tid] = cv.x * wv.x + cv.y * wv.y + cv.z * wv.z + cv.w * wv.w;
    }
    __syncthreads();
    for (int st = 128; st > 0; st >>= 1) {
        if (tid < st)
            #pragma unroll
            for (int cls = 0; cls < 10; ++cls)
                red[cls][tid] += red[cls][tid + st];
        __syncthreads();
    }
    if (tid < 10) out[b * 10 + tid] = red[tid][0] + bV[tid];
}

// ---------------------------------------------------------------- launch
extern "C" void kernel_launch(void* const* d_in, const int* in_sizes, int n_in,
                              void* d_out, int out_size, void* d_ws, size_t ws_size,
                              hipStream_t stream)
{
    const int*   x   = (const int*)d_in[0];
    const float* emb = (const float*)d_in[1];
    const float* Wg  = (const float*)d_in[2];
    const float* bg  = (const float*)d_in[3];
    const float* Wa  = (const float*)d_in[4];
    const float* va  = (const float*)d_in[5];
    const float* WV  = (const float*)d_in[6];
    const float* bV  = (const float*)d_in[7];
    float* out = (float*)d_out;

    char* ws = (char*)d_ws;
    size_t o = 0;
    auto alloc = [&](size_t bytes) { void* p = ws + o; o += (bytes + 255) & ~(size_t)255; return p; };
    f16*      e16   = (f16*)alloc((size_t)Sn * Bn * En * 2);        // 33.5 MB
    f16*      Wa_hi = (f16*)alloc((size_t)Hn * Hn * 2);             // 2 MB
    f16*      h16   = (f16*)alloc((size_t)(Sn + 1) * Bn * Hn * 2);  // 67.2 MB
    float*    energy= (float*)alloc((size_t)Bn * Sn * 4);
    float*    ctx   = (float*)alloc((size_t)Bn * Hn * 4);
    unsigned* bar   = (unsigned*)alloc(4096);
    // total ~103 MB

    hipMemsetAsync(h16, 0, (size_t)Bn * Hn * 2, stream);    // slot 0 = zeros
    hipMemsetAsync(energy, 0, (size_t)Bn * Sn * 4, stream);
    hipMemsetAsync(bar, 0, 4096, stream);

    gather_e_k<<<8192, 256, 0, stream>>>(x, emb, e16);
    split_wa_k<<<512, 256, 0, stream>>>(Wa, Wa_hi);

    lstm_persist_k<<<256, 256, 0, stream>>>(e16, Wg, bg, h16, bar);

    energy_k<<<512 * 8, 256, 0, stream>>>(h16, Wa_hi, va, energy);
    softctx_k<<<Bn, 256, 0, stream>>>(energy, x, h16, ctx);
    logits_k<<<Bn, 256, 0, stream>>>(ctx, WV, bV, out);
}